// Round 2
// baseline (595.311 us; speedup 1.0000x reference)
//
#include <hip/hip_runtime.h>
#include <hip/hip_fp16.h>
#include <math.h>

#define N_NODES 50000
#define MP      50048              /* padded rows = 391*128 */
#define N_EDGES 800000
#define E_TOT   (N_EDGES + N_NODES)
#define EB      ((E_TOT + 255) / 256)   /* 3321 edge blocks in prep */
#define HEADS   4
#define CH      128
#define NOUT    512
#define NEG_SLOPE 0.2f

typedef unsigned int u32;
typedef unsigned short u16;
typedef __attribute__((ext_vector_type(8))) _Float16 f16x8;
typedef __attribute__((ext_vector_type(4))) float f32x4;

// ---------------- prep: edge-degree count + W1/W2 fp32->fp16 cast ----------------

__global__ __launch_bounds__(256) void prep(const int* __restrict__ ei,
                                            int* __restrict__ deg,
                                            const float* __restrict__ W1,
                                            __half* __restrict__ B1,
                                            const float* __restrict__ W2,
                                            __half* __restrict__ B2) {
  int b = blockIdx.x, tid = threadIdx.x;
  if (b < EB) {
    int e = b * 256 + tid;
    if (e < E_TOT) {
      int dst = (e < N_EDGES) ? ei[N_EDGES + e] : (e - N_EDGES);
      atomicAdd(&deg[dst], 1);
    }
    return;
  }
  const float* s; __half* d; int k;
  if (b < EB + 128) { s = W1; d = B1; k = (b - EB) * 256 + tid; }        // 32768 float4
  else              { s = W2; d = B2; k = (b - EB - 128) * 256 + tid; }  // 16384 float4
  float4 v = ((const float4*)s)[k];
  __half2 h01 = __float22half2_rn(make_float2(v.x, v.y));
  __half2 h23 = __float22half2_rn(make_float2(v.z, v.w));
  uint2 pk = make_uint2(*(u32*)&h01, *(u32*)&h23);
  ((uint2*)d)[k] = pk;
}

// single block, 1024 threads: per-thread sequential chunk + one 1024-wide scan
__global__ __launch_bounds__(1024) void scan_deg_fast(const int* __restrict__ deg,
                                                      int* __restrict__ row_ptr) {
  __shared__ int ssum[1024];
  const int tid = threadIdx.x;
  const int CHUNK = (N_NODES + 1023) / 1024;   // 49
  const int base = tid * CHUNK;
  int s = 0;
  for (int i = 0; i < CHUNK; ++i) {
    int idx = base + i;
    if (idx < N_NODES) s += deg[idx];
  }
  ssum[tid] = s;
  __syncthreads();
  for (int off = 1; off < 1024; off <<= 1) {
    int v = (tid >= off) ? ssum[tid - off] : 0;
    __syncthreads();
    ssum[tid] += v;
    __syncthreads();
  }
  int run = (tid > 0) ? ssum[tid - 1] : 0;
  for (int i = 0; i < CHUNK; ++i) {
    int idx = base + i;
    if (idx < N_NODES) { run += deg[idx]; row_ptr[idx + 1] = run; }
  }
  if (tid == 0) row_ptr[0] = 0;
}

__global__ __launch_bounds__(256) void scatter_edges(const int* __restrict__ ei,
                                                     const int* __restrict__ row_ptr,
                                                     int* __restrict__ cursor,
                                                     int* __restrict__ col) {
  int e = blockIdx.x * 256 + threadIdx.x;
  if (e >= E_TOT) return;
  int src, dst;
  if (e < N_EDGES) { src = ei[e]; dst = ei[N_EDGES + e]; }
  else             { src = e - N_EDGES; dst = src; }
  int pos = atomicAdd(&cursor[dst], 1);
  col[row_ptr[dst] + pos] = src;
}

// ---------------- fp16 MFMA GEMM (head-pair blocks) + fused attention epilogue ----
// C_fp16[MP,512] = A[M,K] @ B_fp16[512,K]^T, fp32 accumulate.
// Grid (MP/128, 2): block = 128 rows x 256 cols (one HEAD PAIR) x 512 threads.
// r9: T3-minimum double-buffered pipeline. Old structure staged tile t and
// immediately hit __syncthreads() (compiler emits s_waitcnt vmcnt(0) before
// s_barrier -> FULL staging latency exposed every K-step; R1's occupancy fix
// only let the other block cover part of it). New structure: STAGE(t+1) into
// the other LDS buffer BEFORE computing tile t; counted s_waitcnt vmcnt(N)
// (N = next tile's in-flight loads: 4 for K=256, 3 for K=128) so those loads
// stay in flight across both barriers; raw s_barrier + memory-clobber fences
// replace __syncthreads so the compiler can't re-insert the vmcnt(0) drain.
// LDS: 68 KB (gemm1) / 52 KB (gemm2) -> still 2 blocks/CU at VGPR<=128.
// AF32: stage A as raw fp32 (direct from input x), convert to fp16 in the
// LDS->frag path (RNE). Rows clamped to N_NODES-1.
// Epilogue: per-row <xh,att_s/d> from fp32 accs.

#define GLD16(gp, lp)                                                          \
  __builtin_amdgcn_global_load_lds(                                            \
      (const __attribute__((address_space(1))) u32*)(gp),                      \
      (__attribute__((address_space(3))) u32*)(lp), 16, 0, 0)

// raw barrier with compiler memory fences on both sides (no vmcnt(0) drain)
#define BARRIER()                                  \
  do {                                             \
    asm volatile("" ::: "memory");                 \
    __builtin_amdgcn_s_barrier();                  \
    asm volatile("" ::: "memory");                 \
  } while (0)

template <int K, bool AF32>
__global__ __launch_bounds__(512, 4) void gemm_att(
    const void* __restrict__ Ap, const __half* __restrict__ B,
    const float* __restrict__ att_s, const float* __restrict__ att_d,
    __half* __restrict__ C, float* __restrict__ as_, float* __restrict__ ad_) {
  constexpr int AESZ = AF32 ? 4 : 2;
  constexpr int ASZB = 128 * 32 * AESZ;     // one A buffer: 16 KB (fp32) / 8 KB
  constexpr int BSZB = 256 * 32 * 2;        // one B buffer: 16 KB
  __shared__ char sAraw[2 * ASZB];          // double-buffered
  __shared__ u16  sB[2 * 256 * 32];         // double-buffered
  __shared__ float sAtt[2][8][64];          // 4 KB
  const int tid  = threadIdx.x;             // 0..511
  const int lane = tid & 63;
  const int wave = tid >> 6;                // 0..7
  const int m0 = blockIdx.x * 128;
  const int hb = blockIdx.y;                // head pair: cols hb*256..hb*256+255
  const int n0 = hb * 256;
  const int wm = (wave >> 2) * 64;          // row half
  const int wn = (wave & 3) * 64;           // col quarter
  const int t = lane & 15, quad = lane >> 4;

  f32x4 acc[4][4];
#pragma unroll
  for (int i = 0; i < 4; i++)
#pragma unroll
    for (int j = 0; j < 4; j++) acc[i][j] = (f32x4){0.f, 0.f, 0.f, 0.f};

  constexpr int ACH  = 128 * 32 * AESZ / 16;   // A 16B-chunks per step (1024 or 512)
  constexpr int ACPR = 32 * AESZ / 16;         // A chunks per row (8 or 4)
  constexpr int NA   = ACH / 512;              // A chunks per thread (2 or 1)
  constexpr int NT   = K / 32;                 // K-steps (8 or 4)

  // ---- hoisted staging addresses (k0-invariant; advance per staged step) ----
  const char* gpA[NA]; u32 ldsAoff[NA];
#pragma unroll
  for (int r = 0; r < NA; ++r) {
    int c = tid + r * 512;
    int row = c / ACPR, w16 = c % ACPR;
    int grow = m0 + row;
    if (grow > N_NODES - 1) grow = N_NODES - 1;     // input x is exact-sized
    gpA[r] = (const char*)Ap + (size_t)grow * K * AESZ + w16 * 16;
    ldsAoff[r] = (u32)c * 16;
  }
  const char* gpB[2]; u32 ldsBoff[2];
#pragma unroll
  for (int r = 0; r < 2; ++r) {
    int c = tid + r * 512;
    int row = c >> 2, w16 = c & 3;
    gpB[r] = (const char*)B + (size_t)(n0 + row) * K * 2 + w16 * 16;
    ldsBoff[r] = (u32)c * 16;
  }

  auto stage = [&](int bsel) {
#pragma unroll
    for (int r = 0; r < NA; ++r) {
      GLD16(gpA[r], sAraw + bsel * ASZB + ldsAoff[r]);
      gpA[r] += 32 * AESZ;
    }
#pragma unroll
    for (int r = 0; r < 2; ++r) {
      GLD16(gpB[r], (char*)sB + bsel * BSZB + ldsBoff[r]);
      gpB[r] += 64;
    }
  };

  auto compute = [&](int bsel) {
    f16x8 a[4], b[4];
    const char* abuf = sAraw + bsel * ASZB;
    const u16*  bbuf = sB + bsel * (256 * 32);
#pragma unroll
    for (int i = 0; i < 4; ++i) {
      int ar = wm + t + i * 16;
      if (AF32) {
        const float* fp = (const float*)abuf + ar * 32 + quad * 8;
        f32x4 lo = *(const f32x4*)fp;
        f32x4 hi = *(const f32x4*)(fp + 4);
        f16x8 v;
#pragma unroll
        for (int e2 = 0; e2 < 4; ++e2) {
          v[e2]     = (_Float16)lo[e2];
          v[e2 + 4] = (_Float16)hi[e2];
        }
        a[i] = v;
      } else {
        a[i] = *(const f16x8*)((const u16*)abuf + ar * 32 + quad * 8);
      }
      b[i] = *(const f16x8*)&bbuf[(wn + t + i * 16) * 32 + quad * 8];
    }
#pragma unroll
    for (int i = 0; i < 4; ++i)
#pragma unroll
      for (int j = 0; j < 4; ++j)
        acc[i][j] = __builtin_amdgcn_mfma_f32_16x16x32_f16(a[i], b[j], acc[i][j], 0, 0, 0);
  };

  // ---- pipelined K-loop: stage(t+1) in flight across compute(t) ----
  stage(0);
  int cur = 0;
  for (int kt = 0; kt < NT - 1; ++kt) {
    stage(cur ^ 1);
    // wait for tile kt's loads only; tile kt+1's stay in flight
    if constexpr (AF32) asm volatile("s_waitcnt vmcnt(4)" ::: "memory");
    else                asm volatile("s_waitcnt vmcnt(3)" ::: "memory");
    BARRIER();                 // all waves' tile-kt loads landed
    compute(cur);
    BARRIER();                 // all reads of buf[cur] done before next overwrite
    cur ^= 1;
  }
  asm volatile("s_waitcnt vmcnt(0)" ::: "memory");
  BARRIER();
  compute(cur);

  // ---- att partials: per-row dot with att vectors (head fixed per wave) ----
  const int hloc = wn >> 7;                    // 0/1 within the pair
  const float* asv = att_s + (hb * 2 + hloc) * CH + (wn & 127);
  const float* adv = att_d + (hb * 2 + hloc) * CH + (wn & 127);
#pragma unroll
  for (int i = 0; i < 4; ++i) {
    float sa[4] = {0.f, 0.f, 0.f, 0.f}, sd[4] = {0.f, 0.f, 0.f, 0.f};
#pragma unroll
    for (int j = 0; j < 4; ++j) {
      int c = j * 16 + t;
      float sc = asv[c], dc = adv[c];
#pragma unroll
      for (int r = 0; r < 4; ++r) {
        sa[r] = fmaf(acc[i][j][r], sc, sa[r]);
        sd[r] = fmaf(acc[i][j][r], dc, sd[r]);
      }
    }
#pragma unroll
    for (int r = 0; r < 4; ++r) {
#pragma unroll
      for (int mask = 1; mask < 16; mask <<= 1) {
        sa[r] += __shfl_xor(sa[r], mask, 64);
        sd[r] += __shfl_xor(sd[r], mask, 64);
      }
      if (t == 0) {
        sAtt[0][wave][i * 16 + quad * 4 + r] = sa[r];
        sAtt[1][wave][i * 16 + quad * 4 + r] = sd[r];
      }
    }
  }

  // ---- C stores (C/D layout col=lane&15, row=quad*4+reg) ----
#pragma unroll
  for (int i = 0; i < 4; ++i)
#pragma unroll
    for (int j = 0; j < 4; ++j)
#pragma unroll
      for (int r = 0; r < 4; ++r) {
        int m = m0 + wm + i * 16 + quad * 4 + r;
        int n = n0 + wn + j * 16 + t;
        C[(size_t)m * NOUT + n] = __float2half(acc[i][j][r]);
      }

  __syncthreads();   // sAtt complete (full drain OK once, at kernel end)
  // ---- att finals: combine the two col-waves of each (row-half, head) ----
  if ((wave & 1) == 0) {
    int gm = m0 + (wave >> 2) * 64 + lane;
    int h = hb * 2 + ((wave >> 1) & 1);
    if (gm < N_NODES) {
      as_[gm * HEADS + h] = sAtt[0][wave][lane] + sAtt[0][wave + 1][lane];
      ad_[gm * HEADS + h] = sAtt[1][wave][lane] + sAtt[1][wave + 1][lane];
    }
  }
}

// ---------------- GAT aggregation, fp16 gather ----------------
// one wave per dst node. lane -> (h, 8 channels) => one coalesced 1KB row read
// per edge per wave. At the measured ~11 B/cyc/CU L1-miss service ceiling.
// No explicit segment-max (|alpha|max ~ 8 << 88, algebraically identical).
// HALF_OUT=1: fp16 out (feeds layer-2 GEMM directly). HALF_OUT=0: fp32 out.

template <bool HALF_OUT>
__global__ __launch_bounds__(256) void gat_aggregate_f16(const __half* __restrict__ xh,
                                                         const float* __restrict__ as_,
                                                         const float* __restrict__ ad_,
                                                         const int* __restrict__ row_ptr,
                                                         const int* __restrict__ col,
                                                         const float* __restrict__ bias,
                                                         void* __restrict__ outv) {
  int node = (blockIdx.x * 256 + threadIdx.x) >> 6;
  if (node >= N_NODES) return;
  int lane = threadIdx.x & 63;
  int h = lane >> 4, ls = lane & 15, cb = ls * 8;
  int s = row_ptr[node], e = row_ptr[node + 1];
  float adh = ad_[node * HEADS + h];

  float acc[8];
#pragma unroll
  for (int j = 0; j < 8; j++) acc[j] = 0.f;
  float denom = 0.f;

  auto accum = [&](uint4 q, float w) {
    __half2 q0 = *(__half2*)&q.x, q1 = *(__half2*)&q.y;
    __half2 q2 = *(__half2*)&q.z, q3 = *(__half2*)&q.w;
    float2 f0 = __half22float2(q0), f1 = __half22float2(q1);
    float2 f2 = __half22float2(q2), f3 = __half22float2(q3);
    acc[0] = fmaf(w, f0.x, acc[0]); acc[1] = fmaf(w, f0.y, acc[1]);
    acc[2] = fmaf(w, f1.x, acc[2]); acc[3] = fmaf(w, f1.y, acc[3]);
    acc[4] = fmaf(w, f2.x, acc[4]); acc[5] = fmaf(w, f2.y, acc[5]);
    acc[6] = fmaf(w, f3.x, acc[6]); acc[7] = fmaf(w, f3.y, acc[7]);
  };

  int i = s;
  for (; i + 4 <= e; i += 4) {
    int s0 = col[i], s1 = col[i + 1], s2 = col[i + 2], s3 = col[i + 3];
    float l0 = as_[s0 * HEADS + h];
    float l1 = as_[s1 * HEADS + h];
    float l2 = as_[s2 * HEADS + h];
    float l3 = as_[s3 * HEADS + h];
    uint4 q0 = *(const uint4*)(xh + (size_t)s0 * NOUT + h * CH + cb);
    uint4 q1 = *(const uint4*)(xh + (size_t)s1 * NOUT + h * CH + cb);
    uint4 q2 = *(const uint4*)(xh + (size_t)s2 * NOUT + h * CH + cb);
    uint4 q3 = *(const uint4*)(xh + (size_t)s3 * NOUT + h * CH + cb);
    float a0 = l0 + adh; a0 = (a0 >= 0.f) ? a0 : NEG_SLOPE * a0;
    float a1 = l1 + adh; a1 = (a1 >= 0.f) ? a1 : NEG_SLOPE * a1;
    float a2 = l2 + adh; a2 = (a2 >= 0.f) ? a2 : NEG_SLOPE * a2;
    float a3 = l3 + adh; a3 = (a3 >= 0.f) ? a3 : NEG_SLOPE * a3;
    float w0 = __expf(a0), w1 = __expf(a1), w2 = __expf(a2), w3 = __expf(a3);
    denom += (w0 + w1) + (w2 + w3);
    accum(q0, w0); accum(q1, w1); accum(q2, w2); accum(q3, w3);
  }
  for (; i < e; ++i) {
    int src = col[i];
    float l = as_[src * HEADS + h];
    uint4 q = *(const uint4*)(xh + (size_t)src * NOUT + h * CH + cb);
    float a = l + adh; a = (a >= 0.f) ? a : NEG_SLOPE * a;
    float w = __expf(a);
    denom += w;
    accum(q, w);
  }

  float inv = 1.f / (denom + 1e-16f);
#pragma unroll
  for (int j = 0; j < 8; j++) acc[j] *= inv;

  // mean over heads: butterfly over lane bits 4,5
#pragma unroll
  for (int j = 0; j < 8; j++) {
    acc[j] += __shfl_xor(acc[j], 16, 64);
    acc[j] += __shfl_xor(acc[j], 32, 64);
  }
  if (h == 0) {
    float r[8];
#pragma unroll
    for (int j = 0; j < 8; j++) r[j] = acc[j] * 0.25f + bias[cb + j];
    if (HALF_OUT) {
      __half2 o[4];
#pragma unroll
      for (int j = 0; j < 4; j++)
        o[j] = __float22half2_rn(make_float2(r[2 * j], r[2 * j + 1]));
      *(uint4*)((__half*)outv + (size_t)node * CH + cb) = *(uint4*)o;
    } else {
      float4 o0 = make_float4(r[0], r[1], r[2], r[3]);
      float4 o1 = make_float4(r[4], r[5], r[6], r[7]);
      *(float4*)((float*)outv + (size_t)node * CH + cb)     = o0;
      *(float4*)((float*)outv + (size_t)node * CH + cb + 4) = o1;
    }
  }
}

// ---------------- launch ----------------

extern "C" void kernel_launch(void* const* d_in, const int* in_sizes, int n_in,
                              void* d_out, int out_size, void* d_ws, size_t ws_size,
                              hipStream_t stream) {
  const float* x      = (const float*)d_in[0];
  const int*   ei     = (const int*)  d_in[1];
  const float* W1     = (const float*)d_in[2];
  const float* att_s1 = (const float*)d_in[3];
  const float* att_d1 = (const float*)d_in[4];
  const float* b1     = (const float*)d_in[5];
  const float* W2     = (const float*)d_in[6];
  const float* att_s2 = (const float*)d_in[7];
  const float* att_d2 = (const float*)d_in[8];
  const float* b2     = (const float*)d_in[9];
  float* out = (float*)d_out;

  char* ws = (char*)d_ws;
  size_t off = 0;
  auto alloc = [&](size_t bytes) -> void* {
    void* p = ws + off;
    off += (bytes + 255) & ~(size_t)255;
    return p;
  };
  __half* A2_16  = (__half*)alloc((size_t)MP * 128 * 2);   // 12.8 MB (layer-1 agg out)
  __half* B1_16  = (__half*)alloc((size_t)512 * 256 * 2);
  __half* B2_16  = (__half*)alloc((size_t)512 * 128 * 2);
  __half* xh16   = (__half*)alloc((size_t)MP * NOUT * 2);  // 51.2 MB
  float* as_     = (float*)alloc((size_t)N_NODES * HEADS * 4);
  float* ad_     = (float*)alloc((size_t)N_NODES * HEADS * 4);
  int*   row_ptr = (int*)alloc((size_t)(N_NODES + 1) * 4);
  int*   deg     = (int*)alloc((size_t)N_NODES * 4);       // deg+cursor adjacent:
  int*   cursor  = (int*)alloc((size_t)N_NODES * 4);       // one memset covers both
  int*   col     = (int*)alloc((size_t)E_TOT * 4);

  const int edge_blocks = (E_TOT + 255) / 256;
  const int node_wave_blocks = (N_NODES + 3) / 4;
  dim3 ggrid(MP / 128, 2);   // 391 x 2 head-pair blocks

  // CSR count + W casts fused; deg and cursor zeroed in one memset
  hipMemsetAsync(deg, 0, (size_t)N_NODES * 2 * 4 + 256, stream);
  prep<<<EB + 192, 256, 0, stream>>>(ei, deg, W1, B1_16, W2, B2_16);
  scan_deg_fast<<<1, 1024, 0, stream>>>(deg, row_ptr);
  scatter_edges<<<edge_blocks, 256, 0, stream>>>(ei, row_ptr, cursor, col);

  // layer 1 (A = raw fp32 x, converted in-kernel)
  gemm_att<256, true><<<ggrid, 512, 0, stream>>>(x, B1_16, att_s1, att_d1,
                                                 xh16, as_, ad_);
  gat_aggregate_f16<true><<<node_wave_blocks, 256, 0, stream>>>(
      xh16, as_, ad_, row_ptr, col, b1, A2_16);

  // layer 2 (A = fp16 output of aggregate-1)
  gemm_att<128, false><<<ggrid, 512, 0, stream>>>(A2_16, B2_16, att_s2, att_d2,
                                                  xh16, as_, ad_);
  gat_aggregate_f16<false><<<node_wave_blocks, 256, 0, stream>>>(
      xh16, as_, ad_, row_ptr, col, b2, out);
}

// Round 3
// 553.902 us; speedup vs baseline: 1.0748x; 1.0748x over previous
//
#include <hip/hip_runtime.h>
#include <hip/hip_fp16.h>
#include <math.h>

#define N_NODES 50000
#define MPAD    50176              /* padded rows = 196*256 */
#define N_EDGES 800000
#define E_TOT   (N_EDGES + N_NODES)
#define EB      ((E_TOT + 255) / 256)   /* 3321 edge blocks in prep */
#define HEADS   4
#define NEG_SLOPE 0.2f

typedef unsigned int u32;
typedef unsigned short u16;
typedef __attribute__((ext_vector_type(8))) _Float16 f16x8;
typedef __attribute__((ext_vector_type(4))) float f32x4;

// =====================================================================
// DUAL-FORM GAT (r10): aggregate PRE-transform features, GEMM after.
//   scores:  a_s[n,h] = <x[n], w~s_h>,  w~s_h = att_src_h @ W_h  (tiny)
//   agg_h[dst] = sum_e coef_{e,h} * x[src_e]          (gather 512/256 B/edge
//                                                      instead of 1024 B)
//   out[dst]   = 0.25 * sum_h agg_h @ W_h^T + b       (GEMM on aggregated)
// Layer-2 gather table (h, 12.8 MB fp16) is L2/L3-resident -> FETCH ~ 0.
// =====================================================================

// ---------------- prep: degree count + W permute-casts + w~ = att@W ---------

__global__ __launch_bounds__(256) void prep(const int* __restrict__ ei,
                                            int* __restrict__ deg,
                                            const float* __restrict__ W1,
                                            __half* __restrict__ B1,
                                            const float* __restrict__ W2,
                                            __half* __restrict__ B2,
                                            const float* __restrict__ att_s1,
                                            const float* __restrict__ att_d1,
                                            const float* __restrict__ att_s2,
                                            const float* __restrict__ att_d2,
                                            float* __restrict__ ws1,
                                            float* __restrict__ wd1,
                                            float* __restrict__ ws2,
                                            float* __restrict__ wd2) {
  int b = blockIdx.x, tid = threadIdx.x;
  if (b < EB) {
    int e = b * 256 + tid;
    if (e < E_TOT) {
      int dst = (e < N_EDGES) ? ei[N_EDGES + e] : (e - N_EDGES);
      atomicAdd(&deg[dst], 1);
    }
    return;
  }
  if (b < EB + 128) {
    // W1[512x256] -> B1'[j=0..127][k=h*256+c]: B1'[j][h*256+c] = W1[h*128+j][c]
    int k4 = (b - EB) * 256 + tid;                 // 32768 float4
    float4 v = ((const float4*)W1)[k4];
    __half2 h01 = __float22half2_rn(make_float2(v.x, v.y));
    __half2 h23 = __float22half2_rn(make_float2(v.z, v.w));
    uint2 pk = make_uint2(*(u32*)&h01, *(u32*)&h23);
    int r = k4 >> 6, h = r >> 7, j = r & 127;      // r = W1 row, 4 elems/chunk
    ((uint2*)B1)[j * 256 + h * 64 + (k4 & 63)] = pk;
    return;
  }
  if (b < EB + 192) {
    // W2[512x128] -> B2'[j][h*128+c] = W2[h*128+j][c]
    int k4 = (b - EB - 128) * 256 + tid;           // 16384 float4
    float4 v = ((const float4*)W2)[k4];
    __half2 h01 = __float22half2_rn(make_float2(v.x, v.y));
    __half2 h23 = __float22half2_rn(make_float2(v.z, v.w));
    uint2 pk = make_uint2(*(u32*)&h01, *(u32*)&h23);
    int r = k4 >> 5, h = r >> 7, j = r & 127;
    ((uint2*)B2)[j * 128 + h * 32 + (k4 & 31)] = pk;
    return;
  }
  // w~ vectors: w~[h][k] = sum_c att[h][c] * W[h*128+c][k]
  int bw = b - (EB + 192);                         // 0..15
  int h = bw & 3;
  if (bw < 8) {
    const float* att = (bw < 4) ? att_s1 : att_d1;
    float* o = (bw < 4) ? ws1 : wd1;
    int k = tid;                                   // 0..255
    float acc = 0.f;
    for (int c = 0; c < 128; ++c)
      acc = fmaf(att[h * 128 + c], W1[(size_t)(h * 128 + c) * 256 + k], acc);
    o[h * 256 + k] = acc;
  } else {
    const float* att = (bw < 12) ? att_s2 : att_d2;
    float* o = (bw < 12) ? ws2 : wd2;
    if (tid < 128) {
      int k = tid;
      float acc = 0.f;
      for (int c = 0; c < 128; ++c)
        acc = fmaf(att[h * 128 + c], W2[(size_t)(h * 128 + c) * 128 + k], acc);
      o[h * 128 + k] = acc;
    }
  }
}

// single block, 1024 threads: per-thread sequential chunk + one 1024-wide scan
__global__ __launch_bounds__(1024) void scan_deg_fast(const int* __restrict__ deg,
                                                      int* __restrict__ row_ptr) {
  __shared__ int ssum[1024];
  const int tid = threadIdx.x;
  const int CHUNK = (N_NODES + 1023) / 1024;   // 49
  const int base = tid * CHUNK;
  int s = 0;
  for (int i = 0; i < CHUNK; ++i) {
    int idx = base + i;
    if (idx < N_NODES) s += deg[idx];
  }
  ssum[tid] = s;
  __syncthreads();
  for (int off = 1; off < 1024; off <<= 1) {
    int v = (tid >= off) ? ssum[tid - off] : 0;
    __syncthreads();
    ssum[tid] += v;
    __syncthreads();
  }
  int run = (tid > 0) ? ssum[tid - 1] : 0;
  for (int i = 0; i < CHUNK; ++i) {
    int idx = base + i;
    if (idx < N_NODES) { run += deg[idx]; row_ptr[idx + 1] = run; }
  }
  if (tid == 0) row_ptr[0] = 0;
}

__global__ __launch_bounds__(256) void scatter_edges(const int* __restrict__ ei,
                                                     const int* __restrict__ row_ptr,
                                                     int* __restrict__ cursor,
                                                     int* __restrict__ col) {
  int e = blockIdx.x * 256 + threadIdx.x;
  if (e >= E_TOT) return;
  int src, dst;
  if (e < N_EDGES) { src = ei[e]; dst = ei[N_EDGES + e]; }
  else             { src = e - N_EDGES; dst = src; }
  int pos = atomicAdd(&cursor[dst], 1);
  col[row_ptr[dst] + pos] = src;
}

// ---------------- prep_x: x fp32->fp16 cast + layer-1 scores ----------------
// one wave per node: lane holds 4 channels; 8 dots via full-wave butterfly.

__global__ __launch_bounds__(256) void prep_x(const float* __restrict__ x,
                                              const float* __restrict__ ws1,
                                              const float* __restrict__ wd1,
                                              __half* __restrict__ x16,
                                              float* __restrict__ as_,
                                              float* __restrict__ ad_) {
  int node = (blockIdx.x * 256 + threadIdx.x) >> 6;
  if (node >= N_NODES) return;
  int lane = threadIdx.x & 63;
  int c4 = lane * 4;
  f32x4 xv = *(const f32x4*)(x + (size_t)node * 256 + c4);
  __half2 h01 = __float22half2_rn(make_float2(xv[0], xv[1]));
  __half2 h23 = __float22half2_rn(make_float2(xv[2], xv[3]));
  uint2 pk = make_uint2(*(u32*)&h01, *(u32*)&h23);
  *(uint2*)(x16 + (size_t)node * 256 + c4) = pk;
  float p[8];
#pragma unroll
  for (int v = 0; v < 4; ++v) {
    f32x4 w = *(const f32x4*)(ws1 + v * 256 + c4);
    p[v] = xv[0] * w[0] + xv[1] * w[1] + xv[2] * w[2] + xv[3] * w[3];
    f32x4 u = *(const f32x4*)(wd1 + v * 256 + c4);
    p[4 + v] = xv[0] * u[0] + xv[1] * u[1] + xv[2] * u[2] + xv[3] * u[3];
  }
#pragma unroll
  for (int k = 0; k < 8; ++k)
#pragma unroll
    for (int m = 1; m < 64; m <<= 1)
      p[k] += __shfl_xor(p[k], m, 64);
  if (lane == 0) {
    *(float4*)(as_ + (size_t)node * 4) = make_float4(p[0], p[1], p[2], p[3]);
    *(float4*)(ad_ + (size_t)node * 4) = make_float4(p[4], p[5], p[6], p[7]);
  }
}

// ---------------- score2: layer-2 scores from h (128 ch fp16) ---------------

__global__ __launch_bounds__(256) void score2(const __half* __restrict__ hrow,
                                              const float* __restrict__ ws2,
                                              const float* __restrict__ wd2,
                                              float* __restrict__ as_,
                                              float* __restrict__ ad_) {
  int node = (blockIdx.x * 256 + threadIdx.x) >> 6;
  if (node >= N_NODES) return;
  int lane = threadIdx.x & 63, c = lane * 2;
  float2 f = __half22float2(*(const __half2*)(hrow + (size_t)node * 128 + c));
  float p[8];
#pragma unroll
  for (int v = 0; v < 4; ++v) {
    float2 w = *(const float2*)(ws2 + v * 128 + c);
    p[v] = f.x * w.x + f.y * w.y;
    float2 u = *(const float2*)(wd2 + v * 128 + c);
    p[4 + v] = f.x * u.x + f.y * u.y;
  }
#pragma unroll
  for (int k = 0; k < 8; ++k)
#pragma unroll
    for (int m = 1; m < 64; m <<= 1)
      p[k] += __shfl_xor(p[k], m, 64);
  if (lane == 0) {
    *(float4*)(as_ + (size_t)node * 4) = make_float4(p[0], p[1], p[2], p[3]);
    *(float4*)(ad_ + (size_t)node * 4) = make_float4(p[4], p[5], p[6], p[7]);
  }
}

// ---------------- pre-transform aggregation -------------------------------
// one wave per dst node; lane holds CPL channels of the CHIN-wide input row;
// all 4 heads accumulate from the SAME gathered row (this is the 2-4x byte
// saving vs gathering the 512-ch transformed row). Softmax w/o explicit max
// (|alpha| small, same as previous passing kernels).

template <int CPL>   // 4 -> CHIN=256 (layer 1), 2 -> CHIN=128 (layer 2)
__global__ __launch_bounds__(256) void gat_aggregate_pre(
    const __half* __restrict__ tbl, const float* __restrict__ as_,
    const float* __restrict__ ad_, const int* __restrict__ row_ptr,
    const int* __restrict__ col, __half* __restrict__ agg) {
  constexpr int CHIN = CPL * 64;
  int node = (blockIdx.x * 256 + threadIdx.x) >> 6;
  if (node >= N_NODES) return;
  int lane = threadIdx.x & 63, cb = lane * CPL;
  int s = row_ptr[node], e = row_ptr[node + 1];
  float4 advv = ((const float4*)ad_)[node];
  float adv[4] = {advv.x, advv.y, advv.z, advv.w};
  float acc[4][CPL];
#pragma unroll
  for (int h = 0; h < 4; ++h)
#pragma unroll
    for (int c = 0; c < CPL; ++c) acc[h][c] = 0.f;
  float den[4] = {0.f, 0.f, 0.f, 0.f};

  auto loadq = [&](int src) -> uint2 {
    if (CPL == 4) return *(const uint2*)(tbl + (size_t)src * CHIN + cb);
    uint2 r; r.x = *(const u32*)(tbl + (size_t)src * CHIN + cb); r.y = 0;
    return r;
  };
  auto accum = [&](uint2 q, float4 svv) {
    float sv[4] = {svv.x, svv.y, svv.z, svv.w};
    float w[4];
#pragma unroll
    for (int h = 0; h < 4; ++h) {
      float a = sv[h] + adv[h];
      a = (a >= 0.f) ? a : NEG_SLOPE * a;
      w[h] = __expf(a);
      den[h] += w[h];
    }
    float f[CPL];
    float2 f0 = __half22float2(*(__half2*)&q.x);
    f[0] = f0.x; f[1] = f0.y;
    if (CPL == 4) {
      float2 f1 = __half22float2(*(__half2*)&q.y);
      f[2] = f1.x; f[3] = f1.y;
    }
#pragma unroll
    for (int h = 0; h < 4; ++h)
#pragma unroll
      for (int c = 0; c < CPL; ++c)
        acc[h][c] = fmaf(w[h], f[c], acc[h][c]);
  };

  int i = s;
  for (; i + 4 <= e; i += 4) {
    int s0 = col[i], s1 = col[i + 1], s2 = col[i + 2], s3 = col[i + 3];
    float4 v0 = ((const float4*)as_)[s0];
    float4 v1 = ((const float4*)as_)[s1];
    float4 v2 = ((const float4*)as_)[s2];
    float4 v3 = ((const float4*)as_)[s3];
    uint2 q0 = loadq(s0), q1 = loadq(s1), q2 = loadq(s2), q3 = loadq(s3);
    accum(q0, v0); accum(q1, v1); accum(q2, v2); accum(q3, v3);
  }
  for (; i < e; ++i) {
    int s0 = col[i];
    float4 v0 = ((const float4*)as_)[s0];
    accum(loadq(s0), v0);
  }

#pragma unroll
  for (int h = 0; h < 4; ++h) {
    float inv = 1.f / (den[h] + 1e-16f);
    if (CPL == 4) {
      __half2 o0 = __float22half2_rn(make_float2(acc[h][0] * inv, acc[h][1] * inv));
      __half2 o1 = __float22half2_rn(make_float2(acc[h][2] * inv, acc[h][3] * inv));
      *(uint2*)(agg + (size_t)node * 4 * CHIN + h * CHIN + cb) =
          make_uint2(*(u32*)&o0, *(u32*)&o1);
    } else {
      __half2 o0 = __float22half2_rn(make_float2(acc[h][0] * inv, acc[h][1] * inv));
      *(u32*)(agg + (size_t)node * 4 * CHIN + h * CHIN + cb) = *(u32*)&o0;
    }
  }
}

// ---------------- post-aggregation GEMM: out = 0.25 * A @ B'^T + bias ------
// A[MPAD x K] fp16 (agg, head-concat K), B'[128 x K] fp16, out [MPAD x 128].
// 256x128 tile, 512 thr = 8 waves (4 row x 2 col), 16 MFMA/step/wave.

#define GLD16(gp, lp)                                                          \
  __builtin_amdgcn_global_load_lds(                                            \
      (const __attribute__((address_space(1))) u32*)(gp),                      \
      (__attribute__((address_space(3))) u32*)(lp), 16, 0, 0)

template <int K, bool HALF_OUT>
__global__ __launch_bounds__(512, 4) void gemm_mean(
    const __half* __restrict__ A, const __half* __restrict__ Bm,
    const float* __restrict__ bias, void* __restrict__ outv) {
  __shared__ u16 sA[256 * 32];   // 16 KB
  __shared__ u16 sB[128 * 32];   // 8 KB
  const int tid = threadIdx.x, lane = tid & 63, wave = tid >> 6;
  const int m0 = blockIdx.x * 256;
  const int wm = (wave >> 1) * 64, wn = (wave & 1) * 64;
  const int t = lane & 15, quad = lane >> 4;

  f32x4 acc[4][4];
#pragma unroll
  for (int i = 0; i < 4; i++)
#pragma unroll
    for (int j = 0; j < 4; j++) acc[i][j] = (f32x4){0.f, 0.f, 0.f, 0.f};

  const char* gpA[2]; u32 offA[2];
#pragma unroll
  for (int r = 0; r < 2; ++r) {
    int c = tid + r * 512;              // 1024 chunks: 256 rows x 4
    int row = c >> 2, w16 = c & 3;
    gpA[r] = (const char*)A + ((size_t)(m0 + row) * K) * 2 + w16 * 16;
    offA[r] = (u32)c * 16;
  }
  const char* gpB;
  {
    int row = tid >> 2, w16 = tid & 3;  // 512 chunks: 128 rows x 4
    gpB = (const char*)Bm + ((size_t)row * K) * 2 + w16 * 16;
  }
  u32 offB = (u32)tid * 16;

  for (int k0 = 0; k0 < K; k0 += 32) {
    __syncthreads();
#pragma unroll
    for (int r = 0; r < 2; ++r) { GLD16(gpA[r], (char*)sA + offA[r]); gpA[r] += 64; }
    GLD16(gpB, (char*)sB + offB); gpB += 64;
    __syncthreads();

    f16x8 a[4], b[4];
#pragma unroll
    for (int i = 0; i < 4; ++i) {
      a[i] = *(const f16x8*)&sA[(wm + t + i * 16) * 32 + quad * 8];
      b[i] = *(const f16x8*)&sB[(wn + t + i * 16) * 32 + quad * 8];
    }
#pragma unroll
    for (int i = 0; i < 4; ++i)
#pragma unroll
      for (int j = 0; j < 4; ++j)
        acc[i][j] = __builtin_amdgcn_mfma_f32_16x16x32_f16(a[i], b[j], acc[i][j], 0, 0, 0);
  }

  float bv[4];
#pragma unroll
  for (int j = 0; j < 4; ++j) bv[j] = bias[wn + j * 16 + t];
#pragma unroll
  for (int i = 0; i < 4; ++i)
#pragma unroll
    for (int j = 0; j < 4; ++j)
#pragma unroll
      for (int r = 0; r < 4; ++r) {
        int m = m0 + wm + i * 16 + quad * 4 + r;   // C/D: col=lane&15, row=quad*4+reg
        if (m < N_NODES) {
          int n = wn + j * 16 + t;
          float v = 0.25f * acc[i][j][r] + bv[j];
          if (HALF_OUT) ((__half*)outv)[(size_t)m * 128 + n] = __float2half(v);
          else          ((float*)outv)[(size_t)m * 128 + n] = v;
        }
      }
}

// ---------------- launch ----------------

extern "C" void kernel_launch(void* const* d_in, const int* in_sizes, int n_in,
                              void* d_out, int out_size, void* d_ws, size_t ws_size,
                              hipStream_t stream) {
  const float* x      = (const float*)d_in[0];
  const int*   ei     = (const int*)  d_in[1];
  const float* W1     = (const float*)d_in[2];
  const float* att_s1 = (const float*)d_in[3];
  const float* att_d1 = (const float*)d_in[4];
  const float* b1     = (const float*)d_in[5];
  const float* W2     = (const float*)d_in[6];
  const float* att_s2 = (const float*)d_in[7];
  const float* att_d2 = (const float*)d_in[8];
  const float* b2     = (const float*)d_in[9];
  float* out = (float*)d_out;

  char* ws = (char*)d_ws;
  size_t off = 0;
  auto alloc = [&](size_t bytes) -> void* {
    void* p = ws + off;
    off += (bytes + 255) & ~(size_t)255;
    return p;
  };
  __half* x16  = (__half*)alloc((size_t)MPAD * 256 * 2);    // 25.7 MB
  __half* agg1 = (__half*)alloc((size_t)MPAD * 1024 * 2);   // 102.8 MB
  __half* B1p  = (__half*)alloc((size_t)128 * 1024 * 2);
  __half* B2p  = (__half*)alloc((size_t)128 * 512 * 2);
  float* ws1 = (float*)alloc(4 * 256 * 4);
  float* wd1 = (float*)alloc(4 * 256 * 4);
  float* ws2 = (float*)alloc(4 * 128 * 4);
  float* wd2 = (float*)alloc(4 * 128 * 4);
  float* as1 = (float*)alloc((size_t)N_NODES * 4 * 4);
  float* ad1 = (float*)alloc((size_t)N_NODES * 4 * 4);
  float* as2 = (float*)alloc((size_t)N_NODES * 4 * 4);
  float* ad2 = (float*)alloc((size_t)N_NODES * 4 * 4);
  int*   row_ptr = (int*)alloc((size_t)(N_NODES + 1) * 4);
  int*   deg     = (int*)alloc((size_t)N_NODES * 4);        // deg+cursor adjacent:
  int*   cursor  = (int*)alloc((size_t)N_NODES * 4);        // one memset covers both
  int*   col     = (int*)alloc((size_t)E_TOT * 4);

  // lifetime aliases (stream-ordered, no concurrent use):
  //   out1 (12.8 MB)  reuses x16   (x16 dead after aggregate-1)
  //   agg2 (51.4 MB)  reuses agg1  (agg1 dead after gemm_mean-1)
  __half* out1 = x16;
  __half* agg2 = agg1;

  const int edge_blocks = (E_TOT + 255) / 256;
  const int node_wave_blocks = (N_NODES + 3) / 4;   // 12500

  hipMemsetAsync(deg, 0, (size_t)N_NODES * 2 * 4 + 256, stream);
  prep<<<EB + 208, 256, 0, stream>>>(ei, deg, W1, B1p, W2, B2p,
                                     att_s1, att_d1, att_s2, att_d2,
                                     ws1, wd1, ws2, wd2);
  scan_deg_fast<<<1, 1024, 0, stream>>>(deg, row_ptr);
  scatter_edges<<<edge_blocks, 256, 0, stream>>>(ei, row_ptr, cursor, col);

  // layer 1
  prep_x<<<node_wave_blocks, 256, 0, stream>>>(x, ws1, wd1, x16, as1, ad1);
  gat_aggregate_pre<4><<<node_wave_blocks, 256, 0, stream>>>(
      x16, as1, ad1, row_ptr, col, agg1);
  gemm_mean<1024, true><<<MPAD / 256, 512, 0, stream>>>(agg1, B1p, b1, out1);

  // layer 2
  score2<<<node_wave_blocks, 256, 0, stream>>>(out1, ws2, wd2, as2, ad2);
  gat_aggregate_pre<2><<<node_wave_blocks, 256, 0, stream>>>(
      out1, as2, ad2, row_ptr, col, agg2);
  gemm_mean<512, false><<<MPAD / 256, 512, 0, stream>>>(agg2, B2p, b2, out);
}

// Round 4
// 522.063 us; speedup vs baseline: 1.1403x; 1.0610x over previous
//
#include <hip/hip_runtime.h>
#include <hip/hip_fp16.h>
#include <math.h>

#define N_NODES 50000
#define MPAD    50176              /* padded rows = 196*256 */
#define N_EDGES 800000
#define E_TOT   (N_EDGES + N_NODES)
#define EB      ((E_TOT + 255) / 256)   /* 3321 edge blocks in prep */
#define HEADS   4
#define NEG_SLOPE 0.2f

typedef unsigned int u32;
typedef unsigned short u16;
typedef __attribute__((ext_vector_type(8))) _Float16 f16x8;
typedef __attribute__((ext_vector_type(4))) float f32x4;

// =====================================================================
// DUAL-FORM GAT (r11): aggregate PRE-transform features, GEMM after.
//   scores:  a_s[n,h] = <x[n], w~s_h>,  w~s_h = att_src_h @ W_h  (tiny)
//   w[e,h]  = exp(leaky(a_s[src,h]+a_d[dst,h]))  PRECOMPUTED EDGE-PARALLEL
//             (r11: was recomputed per-lane in agg -> 64x redundant VALU,
//              VALUBusy 84%; weights fp32 in CSR-slot order -> agg math
//              bitwise identical, read as sequential 16B broadcast)
//   agg_h[dst] = sum_e w[e,h] * x[src_e] / den
//   out[dst]   = 0.25 * sum_h agg_h @ W_h^T + b       (GEMM on aggregated)
// =====================================================================

// ---------------- prep: degree count + W permute-casts + w~ = att@W ---------

__global__ __launch_bounds__(256) void prep(const int* __restrict__ ei,
                                            int* __restrict__ deg,
                                            const float* __restrict__ W1,
                                            __half* __restrict__ B1,
                                            const float* __restrict__ W2,
                                            __half* __restrict__ B2,
                                            const float* __restrict__ att_s1,
                                            const float* __restrict__ att_d1,
                                            const float* __restrict__ att_s2,
                                            const float* __restrict__ att_d2,
                                            float* __restrict__ ws1,
                                            float* __restrict__ wd1,
                                            float* __restrict__ ws2,
                                            float* __restrict__ wd2) {
  int b = blockIdx.x, tid = threadIdx.x;
  if (b < EB) {
    int e = b * 256 + tid;
    if (e < E_TOT) {
      int dst = (e < N_EDGES) ? ei[N_EDGES + e] : (e - N_EDGES);
      atomicAdd(&deg[dst], 1);
    }
    return;
  }
  if (b < EB + 128) {
    // W1[512x256] -> B1'[j=0..127][k=h*256+c]: B1'[j][h*256+c] = W1[h*128+j][c]
    int k4 = (b - EB) * 256 + tid;                 // 32768 float4
    float4 v = ((const float4*)W1)[k4];
    __half2 h01 = __float22half2_rn(make_float2(v.x, v.y));
    __half2 h23 = __float22half2_rn(make_float2(v.z, v.w));
    uint2 pk = make_uint2(*(u32*)&h01, *(u32*)&h23);
    int r = k4 >> 6, h = r >> 7, j = r & 127;      // r = W1 row, 4 elems/chunk
    ((uint2*)B1)[j * 256 + h * 64 + (k4 & 63)] = pk;
    return;
  }
  if (b < EB + 192) {
    // W2[512x128] -> B2'[j][h*128+c] = W2[h*128+j][c]
    int k4 = (b - EB - 128) * 256 + tid;           // 16384 float4
    float4 v = ((const float4*)W2)[k4];
    __half2 h01 = __float22half2_rn(make_float2(v.x, v.y));
    __half2 h23 = __float22half2_rn(make_float2(v.z, v.w));
    uint2 pk = make_uint2(*(u32*)&h01, *(u32*)&h23);
    int r = k4 >> 5, h = r >> 7, j = r & 127;
    ((uint2*)B2)[j * 128 + h * 32 + (k4 & 31)] = pk;
    return;
  }
  // w~ vectors: w~[h][k] = sum_c att[h][c] * W[h*128+c][k]
  int bw = b - (EB + 192);                         // 0..15
  int h = bw & 3;
  if (bw < 8) {
    const float* att = (bw < 4) ? att_s1 : att_d1;
    float* o = (bw < 4) ? ws1 : wd1;
    int k = tid;                                   // 0..255
    float acc = 0.f;
    for (int c = 0; c < 128; ++c)
      acc = fmaf(att[h * 128 + c], W1[(size_t)(h * 128 + c) * 256 + k], acc);
    o[h * 256 + k] = acc;
  } else {
    const float* att = (bw < 12) ? att_s2 : att_d2;
    float* o = (bw < 12) ? ws2 : wd2;
    if (tid < 128) {
      int k = tid;
      float acc = 0.f;
      for (int c = 0; c < 128; ++c)
        acc = fmaf(att[h * 128 + c], W2[(size_t)(h * 128 + c) * 128 + k], acc);
      o[h * 128 + k] = acc;
    }
  }
}

// single block, 1024 threads: per-thread sequential chunk + one 1024-wide scan
__global__ __launch_bounds__(1024) void scan_deg_fast(const int* __restrict__ deg,
                                                      int* __restrict__ row_ptr) {
  __shared__ int ssum[1024];
  const int tid = threadIdx.x;
  const int CHUNK = (N_NODES + 1023) / 1024;   // 49
  const int base = tid * CHUNK;
  int s = 0;
  for (int i = 0; i < CHUNK; ++i) {
    int idx = base + i;
    if (idx < N_NODES) s += deg[idx];
  }
  ssum[tid] = s;
  __syncthreads();
  for (int off = 1; off < 1024; off <<= 1) {
    int v = (tid >= off) ? ssum[tid - off] : 0;
    __syncthreads();
    ssum[tid] += v;
    __syncthreads();
  }
  int run = (tid > 0) ? ssum[tid - 1] : 0;
  for (int i = 0; i < CHUNK; ++i) {
    int idx = base + i;
    if (idx < N_NODES) { run += deg[idx]; row_ptr[idx + 1] = run; }
  }
  if (tid == 0) row_ptr[0] = 0;
}

__device__ __forceinline__ float leaky_exp(float a) {
  a = (a >= 0.f) ? a : NEG_SLOPE * a;
  return __expf(a);
}

// scatter + fused layer-1 edge weights (edge-parallel: no per-lane redundancy)
__global__ __launch_bounds__(256) void scatter_edges_w(const int* __restrict__ ei,
                                                       const int* __restrict__ row_ptr,
                                                       int* __restrict__ cursor,
                                                       const float* __restrict__ as_,
                                                       const float* __restrict__ ad_,
                                                       int* __restrict__ col,
                                                       int* __restrict__ dstarr,
                                                       float4* __restrict__ wtab) {
  int e = blockIdx.x * 256 + threadIdx.x;
  if (e >= E_TOT) return;
  int src, dst;
  if (e < N_EDGES) { src = ei[e]; dst = ei[N_EDGES + e]; }
  else             { src = e - N_EDGES; dst = src; }
  int pos = atomicAdd(&cursor[dst], 1);
  int slot = row_ptr[dst] + pos;
  col[slot] = src;
  dstarr[slot] = dst;
  float4 a = ((const float4*)as_)[src];
  float4 d = ((const float4*)ad_)[dst];
  float4 w;
  w.x = leaky_exp(a.x + d.x);
  w.y = leaky_exp(a.y + d.y);
  w.z = leaky_exp(a.z + d.z);
  w.w = leaky_exp(a.w + d.w);
  wtab[slot] = w;
}

// layer-2 edge weights over CSR slots (dst from dstarr)
__global__ __launch_bounds__(256) void edge_weights2(const int* __restrict__ col,
                                                     const int* __restrict__ dstarr,
                                                     const float* __restrict__ as_,
                                                     const float* __restrict__ ad_,
                                                     float4* __restrict__ wtab) {
  int i = blockIdx.x * 256 + threadIdx.x;
  if (i >= E_TOT) return;
  int src = col[i], dst = dstarr[i];
  float4 a = ((const float4*)as_)[src];
  float4 d = ((const float4*)ad_)[dst];
  float4 w;
  w.x = leaky_exp(a.x + d.x);
  w.y = leaky_exp(a.y + d.y);
  w.z = leaky_exp(a.z + d.z);
  w.w = leaky_exp(a.w + d.w);
  wtab[i] = w;
}

// ---------------- prep_x: x fp32->fp16 cast + layer-1 scores ----------------
// one wave per node: lane holds 4 channels; 8 dots via full-wave butterfly.

__global__ __launch_bounds__(256) void prep_x(const float* __restrict__ x,
                                              const float* __restrict__ ws1,
                                              const float* __restrict__ wd1,
                                              __half* __restrict__ x16,
                                              float* __restrict__ as_,
                                              float* __restrict__ ad_) {
  int node = (blockIdx.x * 256 + threadIdx.x) >> 6;
  if (node >= N_NODES) return;
  int lane = threadIdx.x & 63;
  int c4 = lane * 4;
  f32x4 xv = *(const f32x4*)(x + (size_t)node * 256 + c4);
  __half2 h01 = __float22half2_rn(make_float2(xv[0], xv[1]));
  __half2 h23 = __float22half2_rn(make_float2(xv[2], xv[3]));
  uint2 pk = make_uint2(*(u32*)&h01, *(u32*)&h23);
  *(uint2*)(x16 + (size_t)node * 256 + c4) = pk;
  float p[8];
#pragma unroll
  for (int v = 0; v < 4; ++v) {
    f32x4 w = *(const f32x4*)(ws1 + v * 256 + c4);
    p[v] = xv[0] * w[0] + xv[1] * w[1] + xv[2] * w[2] + xv[3] * w[3];
    f32x4 u = *(const f32x4*)(wd1 + v * 256 + c4);
    p[4 + v] = xv[0] * u[0] + xv[1] * u[1] + xv[2] * u[2] + xv[3] * u[3];
  }
#pragma unroll
  for (int k = 0; k < 8; ++k)
#pragma unroll
    for (int m = 1; m < 64; m <<= 1)
      p[k] += __shfl_xor(p[k], m, 64);
  if (lane == 0) {
    *(float4*)(as_ + (size_t)node * 4) = make_float4(p[0], p[1], p[2], p[3]);
    *(float4*)(ad_ + (size_t)node * 4) = make_float4(p[4], p[5], p[6], p[7]);
  }
}

// ---------------- score2: layer-2 scores from h (128 ch fp16) ---------------

__global__ __launch_bounds__(256) void score2(const __half* __restrict__ hrow,
                                              const float* __restrict__ ws2,
                                              const float* __restrict__ wd2,
                                              float* __restrict__ as_,
                                              float* __restrict__ ad_) {
  int node = (blockIdx.x * 256 + threadIdx.x) >> 6;
  if (node >= N_NODES) return;
  int lane = threadIdx.x & 63, c = lane * 2;
  float2 f = __half22float2(*(const __half2*)(hrow + (size_t)node * 128 + c));
  float p[8];
#pragma unroll
  for (int v = 0; v < 4; ++v) {
    float2 w = *(const float2*)(ws2 + v * 128 + c);
    p[v] = f.x * w.x + f.y * w.y;
    float2 u = *(const float2*)(wd2 + v * 128 + c);
    p[4 + v] = f.x * u.x + f.y * u.y;
  }
#pragma unroll
  for (int k = 0; k < 8; ++k)
#pragma unroll
    for (int m = 1; m < 64; m <<= 1)
      p[k] += __shfl_xor(p[k], m, 64);
  if (lane == 0) {
    *(float4*)(as_ + (size_t)node * 4) = make_float4(p[0], p[1], p[2], p[3]);
    *(float4*)(ad_ + (size_t)node * 4) = make_float4(p[4], p[5], p[6], p[7]);
  }
}

// ---------------- pre-transform aggregation with PRECOMPUTED weights -------
// one wave per dst node; lane holds CPL channels; weights w[e,h] read as a
// sequential 16B broadcast (CSR-slot order). readfirstlane on bounds/src ->
// SGPR base + lane-offset gather (saddr), scalarizable col/w loads. Inner
// loop VALU: 16 fma + 4 den-add + 4 cvt (vs ~50 incl. 4x expf in r10).

template <int CPL>   // 4 -> CHIN=256 (layer 1), 2 -> CHIN=128 (layer 2)
__global__ __launch_bounds__(256) void gat_aggregate_w(
    const __half* __restrict__ tbl, const float4* __restrict__ wtab,
    const int* __restrict__ row_ptr, const int* __restrict__ col,
    __half* __restrict__ agg) {
  constexpr int CHIN = CPL * 64;
  int node = (blockIdx.x * 256 + threadIdx.x) >> 6;   // wave-uniform
  if (node >= N_NODES) return;
  int lane = threadIdx.x & 63, cb = lane * CPL;
  const __half* tb = tbl + cb;
  int s = __builtin_amdgcn_readfirstlane(row_ptr[node]);
  int e = __builtin_amdgcn_readfirstlane(row_ptr[node + 1]);

  float acc[4][CPL];
#pragma unroll
  for (int h = 0; h < 4; ++h)
#pragma unroll
    for (int c = 0; c < CPL; ++c) acc[h][c] = 0.f;
  float den[4] = {0.f, 0.f, 0.f, 0.f};

  auto accum = [&](uint2 q, float4 w) {
    float wv[4] = {w.x, w.y, w.z, w.w};
#pragma unroll
    for (int h = 0; h < 4; ++h) den[h] += wv[h];
    float f[CPL];
    float2 f0 = __half22float2(*(__half2*)&q.x);
    f[0] = f0.x; f[1] = f0.y;
    if (CPL == 4) {
      float2 f1 = __half22float2(*(__half2*)&q.y);
      f[2] = f1.x; f[3] = f1.y;
    }
#pragma unroll
    for (int h = 0; h < 4; ++h)
#pragma unroll
      for (int c = 0; c < CPL; ++c)
        acc[h][c] = fmaf(wv[h], f[c], acc[h][c]);
  };
  auto loadq = [&](int src) -> uint2 {
    if (CPL == 4) return *(const uint2*)(tb + (size_t)src * CHIN);
    uint2 r; r.x = *(const u32*)(tb + (size_t)src * CHIN); r.y = 0;
    return r;
  };

  int i = s;
  for (; i + 4 <= e; i += 4) {
    int s0 = __builtin_amdgcn_readfirstlane(col[i]);
    int s1 = __builtin_amdgcn_readfirstlane(col[i + 1]);
    int s2 = __builtin_amdgcn_readfirstlane(col[i + 2]);
    int s3 = __builtin_amdgcn_readfirstlane(col[i + 3]);
    float4 w0 = wtab[i],     w1 = wtab[i + 1];
    float4 w2 = wtab[i + 2], w3 = wtab[i + 3];
    uint2 q0 = loadq(s0), q1 = loadq(s1), q2 = loadq(s2), q3 = loadq(s3);
    accum(q0, w0); accum(q1, w1); accum(q2, w2); accum(q3, w3);
  }
  for (; i < e; ++i) {
    int s0 = __builtin_amdgcn_readfirstlane(col[i]);
    float4 w0 = wtab[i];
    accum(loadq(s0), w0);
  }

#pragma unroll
  for (int h = 0; h < 4; ++h) {
    float inv = 1.f / (den[h] + 1e-16f);
    if (CPL == 4) {
      __half2 o0 = __float22half2_rn(make_float2(acc[h][0] * inv, acc[h][1] * inv));
      __half2 o1 = __float22half2_rn(make_float2(acc[h][2] * inv, acc[h][3] * inv));
      *(uint2*)(agg + (size_t)node * 4 * CHIN + h * CHIN + cb) =
          make_uint2(*(u32*)&o0, *(u32*)&o1);
    } else {
      __half2 o0 = __float22half2_rn(make_float2(acc[h][0] * inv, acc[h][1] * inv));
      *(u32*)(agg + (size_t)node * 4 * CHIN + h * CHIN + cb) = *(u32*)&o0;
    }
  }
}

// ---------------- post-aggregation GEMM: out = 0.25 * A @ B'^T + bias ------
// A[MPAD x K] fp16 (agg, head-concat K), B'[128 x K] fp16, out [MPAD x 128].
// 256x128 tile, 512 thr = 8 waves (4 row x 2 col), 16 MFMA/step/wave.

#define GLD16(gp, lp)                                                          \
  __builtin_amdgcn_global_load_lds(                                            \
      (const __attribute__((address_space(1))) u32*)(gp),                      \
      (__attribute__((address_space(3))) u32*)(lp), 16, 0, 0)

template <int K, bool HALF_OUT>
__global__ __launch_bounds__(512, 4) void gemm_mean(
    const __half* __restrict__ A, const __half* __restrict__ Bm,
    const float* __restrict__ bias, void* __restrict__ outv) {
  __shared__ u16 sA[256 * 32];   // 16 KB
  __shared__ u16 sB[128 * 32];   // 8 KB
  const int tid = threadIdx.x, lane = tid & 63, wave = tid >> 6;
  const int m0 = blockIdx.x * 256;
  const int wm = (wave >> 1) * 64, wn = (wave & 1) * 64;
  const int t = lane & 15, quad = lane >> 4;

  f32x4 acc[4][4];
#pragma unroll
  for (int i = 0; i < 4; i++)
#pragma unroll
    for (int j = 0; j < 4; j++) acc[i][j] = (f32x4){0.f, 0.f, 0.f, 0.f};

  const char* gpA[2]; u32 offA[2];
#pragma unroll
  for (int r = 0; r < 2; ++r) {
    int c = tid + r * 512;              // 1024 chunks: 256 rows x 4
    int row = c >> 2, w16 = c & 3;
    gpA[r] = (const char*)A + ((size_t)(m0 + row) * K) * 2 + w16 * 16;
    offA[r] = (u32)c * 16;
  }
  const char* gpB;
  {
    int row = tid >> 2, w16 = tid & 3;  // 512 chunks: 128 rows x 4
    gpB = (const char*)Bm + ((size_t)row * K) * 2 + w16 * 16;
  }
  u32 offB = (u32)tid * 16;

  for (int k0 = 0; k0 < K; k0 += 32) {
    __syncthreads();
#pragma unroll
    for (int r = 0; r < 2; ++r) { GLD16(gpA[r], (char*)sA + offA[r]); gpA[r] += 64; }
    GLD16(gpB, (char*)sB + offB); gpB += 64;
    __syncthreads();

    f16x8 a[4], b[4];
#pragma unroll
    for (int i = 0; i < 4; ++i) {
      a[i] = *(const f16x8*)&sA[(wm + t + i * 16) * 32 + quad * 8];
      b[i] = *(const f16x8*)&sB[(wn + t + i * 16) * 32 + quad * 8];
    }
#pragma unroll
    for (int i = 0; i < 4; ++i)
#pragma unroll
      for (int j = 0; j < 4; ++j)
        acc[i][j] = __builtin_amdgcn_mfma_f32_16x16x32_f16(a[i], b[j], acc[i][j], 0, 0, 0);
  }

  float bv[4];
#pragma unroll
  for (int j = 0; j < 4; ++j) bv[j] = bias[wn + j * 16 + t];
#pragma unroll
  for (int i = 0; i < 4; ++i)
#pragma unroll
    for (int j = 0; j < 4; ++j)
#pragma unroll
      for (int r = 0; r < 4; ++r) {
        int m = m0 + wm + i * 16 + quad * 4 + r;   // C/D: col=lane&15, row=quad*4+reg
        if (m < N_NODES) {
          int n = wn + j * 16 + t;
          float v = 0.25f * acc[i][j][r] + bv[j];
          if (HALF_OUT) ((__half*)outv)[(size_t)m * 128 + n] = __float2half(v);
          else          ((float*)outv)[(size_t)m * 128 + n] = v;
        }
      }
}

// ---------------- launch ----------------

extern "C" void kernel_launch(void* const* d_in, const int* in_sizes, int n_in,
                              void* d_out, int out_size, void* d_ws, size_t ws_size,
                              hipStream_t stream) {
  const float* x      = (const float*)d_in[0];
  const int*   ei     = (const int*)  d_in[1];
  const float* W1     = (const float*)d_in[2];
  const float* att_s1 = (const float*)d_in[3];
  const float* att_d1 = (const float*)d_in[4];
  const float* b1     = (const float*)d_in[5];
  const float* W2     = (const float*)d_in[6];
  const float* att_s2 = (const float*)d_in[7];
  const float* att_d2 = (const float*)d_in[8];
  const float* b2     = (const float*)d_in[9];
  float* out = (float*)d_out;

  char* ws = (char*)d_ws;
  size_t off = 0;
  auto alloc = [&](size_t bytes) -> void* {
    void* p = ws + off;
    off += (bytes + 255) & ~(size_t)255;
    return p;
  };
  __half* x16  = (__half*)alloc((size_t)MPAD * 256 * 2);    // 25.7 MB
  __half* agg1 = (__half*)alloc((size_t)MPAD * 1024 * 2);   // 102.8 MB
  __half* B1p  = (__half*)alloc((size_t)128 * 1024 * 2);
  __half* B2p  = (__half*)alloc((size_t)128 * 512 * 2);
  float* ws1 = (float*)alloc(4 * 256 * 4);
  float* wd1 = (float*)alloc(4 * 256 * 4);
  float* ws2 = (float*)alloc(4 * 128 * 4);
  float* wd2 = (float*)alloc(4 * 128 * 4);
  float* as1 = (float*)alloc((size_t)N_NODES * 4 * 4);
  float* ad1 = (float*)alloc((size_t)N_NODES * 4 * 4);
  float* as2 = (float*)alloc((size_t)N_NODES * 4 * 4);
  float* ad2 = (float*)alloc((size_t)N_NODES * 4 * 4);
  int*   row_ptr = (int*)alloc((size_t)(N_NODES + 1) * 4);
  int*   deg     = (int*)alloc((size_t)N_NODES * 4);        // deg+cursor adjacent:
  int*   cursor  = (int*)alloc((size_t)N_NODES * 4);        // one memset covers both
  int*   col     = (int*)alloc((size_t)E_TOT * 4);
  int*   dstarr  = (int*)alloc((size_t)E_TOT * 4);
  float4* wtab   = (float4*)alloc((size_t)E_TOT * 16);      // 13.6 MB (reused L2)

  // lifetime aliases (stream-ordered, no concurrent use):
  //   out1 (12.8 MB)  reuses x16   (x16 dead after aggregate-1)
  //   agg2 (51.4 MB)  reuses agg1  (agg1 dead after gemm_mean-1)
  __half* out1 = x16;
  __half* agg2 = agg1;

  const int edge_blocks = (E_TOT + 255) / 256;
  const int node_wave_blocks = (N_NODES + 3) / 4;   // 12500

  hipMemsetAsync(deg, 0, (size_t)N_NODES * 2 * 4 + 256, stream);
  prep<<<EB + 208, 256, 0, stream>>>(ei, deg, W1, B1p, W2, B2p,
                                     att_s1, att_d1, att_s2, att_d2,
                                     ws1, wd1, ws2, wd2);
  scan_deg_fast<<<1, 1024, 0, stream>>>(deg, row_ptr);

  // layer 1 (scores BEFORE scatter so weights fuse into the scatter pass)
  prep_x<<<node_wave_blocks, 256, 0, stream>>>(x, ws1, wd1, x16, as1, ad1);
  scatter_edges_w<<<edge_blocks, 256, 0, stream>>>(ei, row_ptr, cursor,
                                                   as1, ad1, col, dstarr, wtab);
  gat_aggregate_w<4><<<node_wave_blocks, 256, 0, stream>>>(
      x16, wtab, row_ptr, col, agg1);
  gemm_mean<1024, true><<<MPAD / 256, 512, 0, stream>>>(agg1, B1p, b1, out1);

  // layer 2
  score2<<<node_wave_blocks, 256, 0, stream>>>(out1, ws2, wd2, as2, ad2);
  edge_weights2<<<edge_blocks, 256, 0, stream>>>(col, dstarr, as2, ad2, wtab);
  gat_aggregate_w<2><<<node_wave_blocks, 256, 0, stream>>>(
      out1, wtab, row_ptr, col, agg2);
  gemm_mean<512, false><<<MPAD / 256, 512, 0, stream>>>(agg2, B2p, b2, out);
}

// Round 5
// 440.057 us; speedup vs baseline: 1.3528x; 1.1864x over previous
//
#include <hip/hip_runtime.h>
#include <hip/hip_fp16.h>
#include <math.h>

#define N_NODES 50000
#define MPAD    50176              /* padded rows = 196*256 */
#define N_EDGES 800000
#define E_TOT   (N_EDGES + N_NODES)
#define EB      ((E_TOT + 255) / 256)   /* 3321 edge blocks in prep */
#define HEADS   4
#define NEG_SLOPE 0.2f
#define SBLK    ((N_NODES + 255) / 256)  /* 196 scan blocks */

typedef unsigned int u32;
typedef unsigned short u16;
typedef __attribute__((ext_vector_type(8))) _Float16 f16x8;
typedef __attribute__((ext_vector_type(4))) float f32x4;

// =====================================================================
// DUAL-FORM GAT (r12): aggregate PRE-transform features, GEMM after.
//   scores:  a_s[n,h] = <x[n], w~s_h>,  w~s_h = att_src_h @ W_h  (tiny)
//   w[e,h]  = exp(leaky(a_s[src,h]+a_d[dst,h]))  precomputed edge-parallel
//   agg_h[dst] = sum_e w[e,h] * x[src_e] / den
//   out[dst]   = 0.25 * sum_h agg_h @ W_h^T + b       (GEMM on aggregated)
// r12: the 1-block serial degree scan (95 us on ONE CU, 0.16% occupancy —
// largest dispatch after r11 shrank the aggregates) replaced by a 3-launch
// device-wide scan (196 blocks coalesced + 1-block top scan + offset add),
// ~2-4 us each. Everything else identical to r11.
// =====================================================================

// ---------------- prep: degree count + W permute-casts + w~ = att@W ---------

__global__ __launch_bounds__(256) void prep(const int* __restrict__ ei,
                                            int* __restrict__ deg,
                                            const float* __restrict__ W1,
                                            __half* __restrict__ B1,
                                            const float* __restrict__ W2,
                                            __half* __restrict__ B2,
                                            const float* __restrict__ att_s1,
                                            const float* __restrict__ att_d1,
                                            const float* __restrict__ att_s2,
                                            const float* __restrict__ att_d2,
                                            float* __restrict__ ws1,
                                            float* __restrict__ wd1,
                                            float* __restrict__ ws2,
                                            float* __restrict__ wd2) {
  int b = blockIdx.x, tid = threadIdx.x;
  if (b < EB) {
    int e = b * 256 + tid;
    if (e < E_TOT) {
      int dst = (e < N_EDGES) ? ei[N_EDGES + e] : (e - N_EDGES);
      atomicAdd(&deg[dst], 1);
    }
    return;
  }
  if (b < EB + 128) {
    // W1[512x256] -> B1'[j=0..127][k=h*256+c]: B1'[j][h*256+c] = W1[h*128+j][c]
    int k4 = (b - EB) * 256 + tid;                 // 32768 float4
    float4 v = ((const float4*)W1)[k4];
    __half2 h01 = __float22half2_rn(make_float2(v.x, v.y));
    __half2 h23 = __float22half2_rn(make_float2(v.z, v.w));
    uint2 pk = make_uint2(*(u32*)&h01, *(u32*)&h23);
    int r = k4 >> 6, h = r >> 7, j = r & 127;      // r = W1 row, 4 elems/chunk
    ((uint2*)B1)[j * 256 + h * 64 + (k4 & 63)] = pk;
    return;
  }
  if (b < EB + 192) {
    // W2[512x128] -> B2'[j][h*128+c] = W2[h*128+j][c]
    int k4 = (b - EB - 128) * 256 + tid;           // 16384 float4
    float4 v = ((const float4*)W2)[k4];
    __half2 h01 = __float22half2_rn(make_float2(v.x, v.y));
    __half2 h23 = __float22half2_rn(make_float2(v.z, v.w));
    uint2 pk = make_uint2(*(u32*)&h01, *(u32*)&h23);
    int r = k4 >> 5, h = r >> 7, j = r & 127;
    ((uint2*)B2)[j * 128 + h * 32 + (k4 & 31)] = pk;
    return;
  }
  // w~ vectors: w~[h][k] = sum_c att[h][c] * W[h*128+c][k]
  int bw = b - (EB + 192);                         // 0..15
  int h = bw & 3;
  if (bw < 8) {
    const float* att = (bw < 4) ? att_s1 : att_d1;
    float* o = (bw < 4) ? ws1 : wd1;
    int k = tid;                                   // 0..255
    float acc = 0.f;
    for (int c = 0; c < 128; ++c)
      acc = fmaf(att[h * 128 + c], W1[(size_t)(h * 128 + c) * 256 + k], acc);
    o[h * 256 + k] = acc;
  } else {
    const float* att = (bw < 12) ? att_s2 : att_d2;
    float* o = (bw < 12) ? ws2 : wd2;
    if (tid < 128) {
      int k = tid;
      float acc = 0.f;
      for (int c = 0; c < 128; ++c)
        acc = fmaf(att[h * 128 + c], W2[(size_t)(h * 128 + c) * 128 + k], acc);
      o[h * 128 + k] = acc;
    }
  }
}

// ---------------- device-wide degree scan (3 tiny launches) ----------------

__global__ __launch_bounds__(256) void scan_blocks(const int* __restrict__ deg,
                                                   int* __restrict__ row_ptr,
                                                   int* __restrict__ bsum) {
  __shared__ int sh[256];
  int tid = threadIdx.x;
  int idx = blockIdx.x * 256 + tid;
  int v = (idx < N_NODES) ? deg[idx] : 0;
  sh[tid] = v;
  __syncthreads();
#pragma unroll
  for (int off = 1; off < 256; off <<= 1) {
    int t = (tid >= off) ? sh[tid - off] : 0;
    __syncthreads();
    sh[tid] += t;
    __syncthreads();
  }
  if (idx < N_NODES) row_ptr[idx + 1] = sh[tid];
  if (tid == 255) bsum[blockIdx.x] = sh[255];
}

__global__ __launch_bounds__(256) void scan_tops(int* __restrict__ bsum) {
  __shared__ int sh[256];
  int tid = threadIdx.x;
  int v = (tid < SBLK) ? bsum[tid] : 0;
  sh[tid] = v;
  __syncthreads();
#pragma unroll
  for (int off = 1; off < 256; off <<= 1) {
    int t = (tid >= off) ? sh[tid - off] : 0;
    __syncthreads();
    sh[tid] += t;
    __syncthreads();
  }
  if (tid < SBLK) bsum[tid] = sh[tid] - v;   // exclusive
}

__global__ __launch_bounds__(256) void scan_add(const int* __restrict__ bsum,
                                                int* __restrict__ row_ptr) {
  int idx = blockIdx.x * 256 + threadIdx.x;
  int off = bsum[blockIdx.x];
  if (idx < N_NODES) row_ptr[idx + 1] += off;
  if (idx == 0) row_ptr[0] = 0;
}

__device__ __forceinline__ float leaky_exp(float a) {
  a = (a >= 0.f) ? a : NEG_SLOPE * a;
  return __expf(a);
}

// scatter + fused layer-1 edge weights (edge-parallel: no per-lane redundancy)
__global__ __launch_bounds__(256) void scatter_edges_w(const int* __restrict__ ei,
                                                       const int* __restrict__ row_ptr,
                                                       int* __restrict__ cursor,
                                                       const float* __restrict__ as_,
                                                       const float* __restrict__ ad_,
                                                       int* __restrict__ col,
                                                       int* __restrict__ dstarr,
                                                       float4* __restrict__ wtab) {
  int e = blockIdx.x * 256 + threadIdx.x;
  if (e >= E_TOT) return;
  int src, dst;
  if (e < N_EDGES) { src = ei[e]; dst = ei[N_EDGES + e]; }
  else             { src = e - N_EDGES; dst = src; }
  int pos = atomicAdd(&cursor[dst], 1);
  int slot = row_ptr[dst] + pos;
  col[slot] = src;
  dstarr[slot] = dst;
  float4 a = ((const float4*)as_)[src];
  float4 d = ((const float4*)ad_)[dst];
  float4 w;
  w.x = leaky_exp(a.x + d.x);
  w.y = leaky_exp(a.y + d.y);
  w.z = leaky_exp(a.z + d.z);
  w.w = leaky_exp(a.w + d.w);
  wtab[slot] = w;
}

// layer-2 edge weights over CSR slots (dst from dstarr)
__global__ __launch_bounds__(256) void edge_weights2(const int* __restrict__ col,
                                                     const int* __restrict__ dstarr,
                                                     const float* __restrict__ as_,
                                                     const float* __restrict__ ad_,
                                                     float4* __restrict__ wtab) {
  int i = blockIdx.x * 256 + threadIdx.x;
  if (i >= E_TOT) return;
  int src = col[i], dst = dstarr[i];
  float4 a = ((const float4*)as_)[src];
  float4 d = ((const float4*)ad_)[dst];
  float4 w;
  w.x = leaky_exp(a.x + d.x);
  w.y = leaky_exp(a.y + d.y);
  w.z = leaky_exp(a.z + d.z);
  w.w = leaky_exp(a.w + d.w);
  wtab[i] = w;
}

// ---------------- prep_x: x fp32->fp16 cast + layer-1 scores ----------------
// one wave per node: lane holds 4 channels; 8 dots via full-wave butterfly.

__global__ __launch_bounds__(256) void prep_x(const float* __restrict__ x,
                                              const float* __restrict__ ws1,
                                              const float* __restrict__ wd1,
                                              __half* __restrict__ x16,
                                              float* __restrict__ as_,
                                              float* __restrict__ ad_) {
  int node = (blockIdx.x * 256 + threadIdx.x) >> 6;
  if (node >= N_NODES) return;
  int lane = threadIdx.x & 63;
  int c4 = lane * 4;
  f32x4 xv = *(const f32x4*)(x + (size_t)node * 256 + c4);
  __half2 h01 = __float22half2_rn(make_float2(xv[0], xv[1]));
  __half2 h23 = __float22half2_rn(make_float2(xv[2], xv[3]));
  uint2 pk = make_uint2(*(u32*)&h01, *(u32*)&h23);
  *(uint2*)(x16 + (size_t)node * 256 + c4) = pk;
  float p[8];
#pragma unroll
  for (int v = 0; v < 4; ++v) {
    f32x4 w = *(const f32x4*)(ws1 + v * 256 + c4);
    p[v] = xv[0] * w[0] + xv[1] * w[1] + xv[2] * w[2] + xv[3] * w[3];
    f32x4 u = *(const f32x4*)(wd1 + v * 256 + c4);
    p[4 + v] = xv[0] * u[0] + xv[1] * u[1] + xv[2] * u[2] + xv[3] * u[3];
  }
#pragma unroll
  for (int k = 0; k < 8; ++k)
#pragma unroll
    for (int m = 1; m < 64; m <<= 1)
      p[k] += __shfl_xor(p[k], m, 64);
  if (lane == 0) {
    *(float4*)(as_ + (size_t)node * 4) = make_float4(p[0], p[1], p[2], p[3]);
    *(float4*)(ad_ + (size_t)node * 4) = make_float4(p[4], p[5], p[6], p[7]);
  }
}

// ---------------- score2: layer-2 scores from h (128 ch fp16) ---------------

__global__ __launch_bounds__(256) void score2(const __half* __restrict__ hrow,
                                              const float* __restrict__ ws2,
                                              const float* __restrict__ wd2,
                                              float* __restrict__ as_,
                                              float* __restrict__ ad_) {
  int node = (blockIdx.x * 256 + threadIdx.x) >> 6;
  if (node >= N_NODES) return;
  int lane = threadIdx.x & 63, c = lane * 2;
  float2 f = __half22float2(*(const __half2*)(hrow + (size_t)node * 128 + c));
  float p[8];
#pragma unroll
  for (int v = 0; v < 4; ++v) {
    float2 w = *(const float2*)(ws2 + v * 128 + c);
    p[v] = f.x * w.x + f.y * w.y;
    float2 u = *(const float2*)(wd2 + v * 128 + c);
    p[4 + v] = f.x * u.x + f.y * u.y;
  }
#pragma unroll
  for (int k = 0; k < 8; ++k)
#pragma unroll
    for (int m = 1; m < 64; m <<= 1)
      p[k] += __shfl_xor(p[k], m, 64);
  if (lane == 0) {
    *(float4*)(as_ + (size_t)node * 4) = make_float4(p[0], p[1], p[2], p[3]);
    *(float4*)(ad_ + (size_t)node * 4) = make_float4(p[4], p[5], p[6], p[7]);
  }
}

// ---------------- pre-transform aggregation with PRECOMPUTED weights -------
// one wave per dst node; lane holds CPL channels; weights w[e,h] read as a
// sequential 16B broadcast (CSR-slot order). readfirstlane on bounds/src ->
// SGPR base + lane-offset gather (saddr), scalarizable col/w loads.

template <int CPL>   // 4 -> CHIN=256 (layer 1), 2 -> CHIN=128 (layer 2)
__global__ __launch_bounds__(256) void gat_aggregate_w(
    const __half* __restrict__ tbl, const float4* __restrict__ wtab,
    const int* __restrict__ row_ptr, const int* __restrict__ col,
    __half* __restrict__ agg) {
  constexpr int CHIN = CPL * 64;
  int node = (blockIdx.x * 256 + threadIdx.x) >> 6;   // wave-uniform
  if (node >= N_NODES) return;
  int lane = threadIdx.x & 63, cb = lane * CPL;
  const __half* tb = tbl + cb;
  int s = __builtin_amdgcn_readfirstlane(row_ptr[node]);
  int e = __builtin_amdgcn_readfirstlane(row_ptr[node + 1]);

  float acc[4][CPL];
#pragma unroll
  for (int h = 0; h < 4; ++h)
#pragma unroll
    for (int c = 0; c < CPL; ++c) acc[h][c] = 0.f;
  float den[4] = {0.f, 0.f, 0.f, 0.f};

  auto accum = [&](uint2 q, float4 w) {
    float wv[4] = {w.x, w.y, w.z, w.w};
#pragma unroll
    for (int h = 0; h < 4; ++h) den[h] += wv[h];
    float f[CPL];
    float2 f0 = __half22float2(*(__half2*)&q.x);
    f[0] = f0.x; f[1] = f0.y;
    if (CPL == 4) {
      float2 f1 = __half22float2(*(__half2*)&q.y);
      f[2] = f1.x; f[3] = f1.y;
    }
#pragma unroll
    for (int h = 0; h < 4; ++h)
#pragma unroll
      for (int c = 0; c < CPL; ++c)
        acc[h][c] = fmaf(wv[h], f[c], acc[h][c]);
  };
  auto loadq = [&](int src) -> uint2 {
    if (CPL == 4) return *(const uint2*)(tb + (size_t)src * CHIN);
    uint2 r; r.x = *(const u32*)(tb + (size_t)src * CHIN); r.y = 0;
    return r;
  };

  int i = s;
  for (; i + 4 <= e; i += 4) {
    int s0 = __builtin_amdgcn_readfirstlane(col[i]);
    int s1 = __builtin_amdgcn_readfirstlane(col[i + 1]);
    int s2 = __builtin_amdgcn_readfirstlane(col[i + 2]);
    int s3 = __builtin_amdgcn_readfirstlane(col[i + 3]);
    float4 w0 = wtab[i],     w1 = wtab[i + 1];
    float4 w2 = wtab[i + 2], w3 = wtab[i + 3];
    uint2 q0 = loadq(s0), q1 = loadq(s1), q2 = loadq(s2), q3 = loadq(s3);
    accum(q0, w0); accum(q1, w1); accum(q2, w2); accum(q3, w3);
  }
  for (; i < e; ++i) {
    int s0 = __builtin_amdgcn_readfirstlane(col[i]);
    float4 w0 = wtab[i];
    accum(loadq(s0), w0);
  }

#pragma unroll
  for (int h = 0; h < 4; ++h) {
    float inv = 1.f / (den[h] + 1e-16f);
    if (CPL == 4) {
      __half2 o0 = __float22half2_rn(make_float2(acc[h][0] * inv, acc[h][1] * inv));
      __half2 o1 = __float22half2_rn(make_float2(acc[h][2] * inv, acc[h][3] * inv));
      *(uint2*)(agg + (size_t)node * 4 * CHIN + h * CHIN + cb) =
          make_uint2(*(u32*)&o0, *(u32*)&o1);
    } else {
      __half2 o0 = __float22half2_rn(make_float2(acc[h][0] * inv, acc[h][1] * inv));
      *(u32*)(agg + (size_t)node * 4 * CHIN + h * CHIN + cb) = *(u32*)&o0;
    }
  }
}

// ---------------- post-aggregation GEMM: out = 0.25 * A @ B'^T + bias ------
// A[MPAD x K] fp16 (agg, head-concat K), B'[128 x K] fp16, out [MPAD x 128].
// 256x128 tile, 512 thr = 8 waves (4 row x 2 col), 16 MFMA/step/wave.

#define GLD16(gp, lp)                                                          \
  __builtin_amdgcn_global_load_lds(                                            \
      (const __attribute__((address_space(1))) u32*)(gp),                      \
      (__attribute__((address_space(3))) u32*)(lp), 16, 0, 0)

template <int K, bool HALF_OUT>
__global__ __launch_bounds__(512, 4) void gemm_mean(
    const __half* __restrict__ A, const __half* __restrict__ Bm,
    const float* __restrict__ bias, void* __restrict__ outv) {
  __shared__ u16 sA[256 * 32];   // 16 KB
  __shared__ u16 sB[128 * 32];   // 8 KB
  const int tid = threadIdx.x, lane = tid & 63, wave = tid >> 6;
  const int m0 = blockIdx.x * 256;
  const int wm = (wave >> 1) * 64, wn = (wave & 1) * 64;
  const int t = lane & 15, quad = lane >> 4;

  f32x4 acc[4][4];
#pragma unroll
  for (int i = 0; i < 4; i++)
#pragma unroll
    for (int j = 0; j < 4; j++) acc[i][j] = (f32x4){0.f, 0.f, 0.f, 0.f};

  const char* gpA[2]; u32 offA[2];
#pragma unroll
  for (int r = 0; r < 2; ++r) {
    int c = tid + r * 512;              // 1024 chunks: 256 rows x 4
    int row = c >> 2, w16 = c & 3;
    gpA[r] = (const char*)A + ((size_t)(m0 + row) * K) * 2 + w16 * 16;
    offA[r] = (u32)c * 16;
  }
  const char* gpB;
  {
    int row = tid >> 2, w16 = tid & 3;  // 512 chunks: 128 rows x 4
    gpB = (const char*)Bm + ((size_t)row * K) * 2 + w16 * 16;
  }
  u32 offB = (u32)tid * 16;

  for (int k0 = 0; k0 < K; k0 += 32) {
    __syncthreads();
#pragma unroll
    for (int r = 0; r < 2; ++r) { GLD16(gpA[r], (char*)sA + offA[r]); gpA[r] += 64; }
    GLD16(gpB, (char*)sB + offB); gpB += 64;
    __syncthreads();

    f16x8 a[4], b[4];
#pragma unroll
    for (int i = 0; i < 4; ++i) {
      a[i] = *(const f16x8*)&sA[(wm + t + i * 16) * 32 + quad * 8];
      b[i] = *(const f16x8*)&sB[(wn + t + i * 16) * 32 + quad * 8];
    }
#pragma unroll
    for (int i = 0; i < 4; ++i)
#pragma unroll
      for (int j = 0; j < 4; ++j)
        acc[i][j] = __builtin_amdgcn_mfma_f32_16x16x32_f16(a[i], b[j], acc[i][j], 0, 0, 0);
  }

  float bv[4];
#pragma unroll
  for (int j = 0; j < 4; ++j) bv[j] = bias[wn + j * 16 + t];
#pragma unroll
  for (int i = 0; i < 4; ++i)
#pragma unroll
    for (int j = 0; j < 4; ++j)
#pragma unroll
      for (int r = 0; r < 4; ++r) {
        int m = m0 + wm + i * 16 + quad * 4 + r;   // C/D: col=lane&15, row=quad*4+reg
        if (m < N_NODES) {
          int n = wn + j * 16 + t;
          float v = 0.25f * acc[i][j][r] + bv[j];
          if (HALF_OUT) ((__half*)outv)[(size_t)m * 128 + n] = __float2half(v);
          else          ((float*)outv)[(size_t)m * 128 + n] = v;
        }
      }
}

// ---------------- launch ----------------

extern "C" void kernel_launch(void* const* d_in, const int* in_sizes, int n_in,
                              void* d_out, int out_size, void* d_ws, size_t ws_size,
                              hipStream_t stream) {
  const float* x      = (const float*)d_in[0];
  const int*   ei     = (const int*)  d_in[1];
  const float* W1     = (const float*)d_in[2];
  const float* att_s1 = (const float*)d_in[3];
  const float* att_d1 = (const float*)d_in[4];
  const float* b1     = (const float*)d_in[5];
  const float* W2     = (const float*)d_in[6];
  const float* att_s2 = (const float*)d_in[7];
  const float* att_d2 = (const float*)d_in[8];
  const float* b2     = (const float*)d_in[9];
  float* out = (float*)d_out;

  char* ws = (char*)d_ws;
  size_t off = 0;
  auto alloc = [&](size_t bytes) -> void* {
    void* p = ws + off;
    off += (bytes + 255) & ~(size_t)255;
    return p;
  };
  __half* x16  = (__half*)alloc((size_t)MPAD * 256 * 2);    // 25.7 MB
  __half* agg1 = (__half*)alloc((size_t)MPAD * 1024 * 2);   // 102.8 MB
  __half* B1p  = (__half*)alloc((size_t)128 * 1024 * 2);
  __half* B2p  = (__half*)alloc((size_t)128 * 512 * 2);
  float* ws1 = (float*)alloc(4 * 256 * 4);
  float* wd1 = (float*)alloc(4 * 256 * 4);
  float* ws2 = (float*)alloc(4 * 128 * 4);
  float* wd2 = (float*)alloc(4 * 128 * 4);
  float* as1 = (float*)alloc((size_t)N_NODES * 4 * 4);
  float* ad1 = (float*)alloc((size_t)N_NODES * 4 * 4);
  float* as2 = (float*)alloc((size_t)N_NODES * 4 * 4);
  float* ad2 = (float*)alloc((size_t)N_NODES * 4 * 4);
  int*   row_ptr = (int*)alloc((size_t)(N_NODES + 1) * 4);
  int*   deg     = (int*)alloc((size_t)N_NODES * 4);        // deg+cursor adjacent:
  int*   cursor  = (int*)alloc((size_t)N_NODES * 4);        // one memset covers both
  int*   bsum    = (int*)alloc((size_t)256 * 4);
  int*   col     = (int*)alloc((size_t)E_TOT * 4);
  int*   dstarr  = (int*)alloc((size_t)E_TOT * 4);
  float4* wtab   = (float4*)alloc((size_t)E_TOT * 16);      // 13.6 MB (reused L2)

  // lifetime aliases (stream-ordered, no concurrent use):
  //   out1 (12.8 MB)  reuses x16   (x16 dead after aggregate-1)
  //   agg2 (51.4 MB)  reuses agg1  (agg1 dead after gemm_mean-1)
  __half* out1 = x16;
  __half* agg2 = agg1;

  const int edge_blocks = (E_TOT + 255) / 256;
  const int node_wave_blocks = (N_NODES + 3) / 4;   // 12500

  hipMemsetAsync(deg, 0, (size_t)N_NODES * 2 * 4 + 256, stream);
  prep<<<EB + 208, 256, 0, stream>>>(ei, deg, W1, B1p, W2, B2p,
                                     att_s1, att_d1, att_s2, att_d2,
                                     ws1, wd1, ws2, wd2);
  scan_blocks<<<SBLK, 256, 0, stream>>>(deg, row_ptr, bsum);
  scan_tops<<<1, 256, 0, stream>>>(bsum);
  scan_add<<<SBLK, 256, 0, stream>>>(bsum, row_ptr);

  // layer 1 (scores BEFORE scatter so weights fuse into the scatter pass)
  prep_x<<<node_wave_blocks, 256, 0, stream>>>(x, ws1, wd1, x16, as1, ad1);
  scatter_edges_w<<<edge_blocks, 256, 0, stream>>>(ei, row_ptr, cursor,
                                                   as1, ad1, col, dstarr, wtab);
  gat_aggregate_w<4><<<node_wave_blocks, 256, 0, stream>>>(
      x16, wtab, row_ptr, col, agg1);
  gemm_mean<1024, true><<<MPAD / 256, 512, 0, stream>>>(agg1, B1p, b1, out1);

  // layer 2
  score2<<<node_wave_blocks, 256, 0, stream>>>(out1, ws2, wd2, as2, ad2);
  edge_weights2<<<edge_blocks, 256, 0, stream>>>(col, dstarr, as2, ad2, wtab);
  gat_aggregate_w<2><<<node_wave_blocks, 256, 0, stream>>>(
      out1, wtab, row_ptr, col, agg2);
  gemm_mean<512, false><<<MPAD / 256, 512, 0, stream>>>(agg2, B2p, b2, out);
}

// Round 7
// 406.609 us; speedup vs baseline: 1.4641x; 1.0823x over previous
//
#include <hip/hip_runtime.h>
#include <hip/hip_fp16.h>
#include <math.h>

#define N_NODES 50000
#define MPAD    50176              /* padded rows = 196*256 */
#define N_EDGES 800000
#define E_TOT   (N_EDGES + N_NODES)
#define EB      ((E_TOT + 255) / 256)   /* 3321 edge blocks in prep */
#define HEADS   4
#define NEG_SLOPE 0.2f
#define SBLK    ((N_NODES + 255) / 256)  /* 196 scan blocks */

typedef unsigned int u32;
typedef unsigned short u16;
typedef __attribute__((ext_vector_type(8))) _Float16 f16x8;
typedef __attribute__((ext_vector_type(4))) float f32x4;

// =====================================================================
// DUAL-FORM GAT (r13, resubmit after infra failure): aggregate
// PRE-transform features, GEMM after.
//   scores:  a_s[n,h] = <x[n], w~s_h>,  w~s_h = att_src_h @ W_h  (tiny)
//   w[e,h]  = exp(leaky(a_s[src,h]+a_d[dst,h]))  computed in CSR-SLOT order
//   agg_h[dst] = sum_e w[e,h] * x[src_e] / den
//   out[dst]   = 0.25 * sum_h agg_h @ W_h^T + b       (GEMM on aggregated)
// r13: scatter was write-amplification-bound (24B scattered/edge -> 107 MB
// WRITE for a 20 MB footprint, 72 us at 26% HBM / 1.3% VALU). Now:
//   - prep's degree atomicAdd RESULT is saved (epos) -> scatter needs no
//     atomics: slot = row_ptr[dst] + epos[e]
//   - scatter writes one packed int2 (src,dst) = 8B/edge (was 24B, 3 streams)
//   - wtab computed slot-order (coalesced) by one shared edge_weights kernel
//     (dst reads are CSR-sorted -> nearly sequential)
// =====================================================================

// ---------------- prep: degree count (+epos) + W permute-casts + w~ ---------

__global__ __launch_bounds__(256) void prep(const int* __restrict__ ei,
                                            int* __restrict__ deg,
                                            int* __restrict__ epos,
                                            const float* __restrict__ W1,
                                            __half* __restrict__ B1,
                                            const float* __restrict__ W2,
                                            __half* __restrict__ B2,
                                            const float* __restrict__ att_s1,
                                            const float* __restrict__ att_d1,
                                            const float* __restrict__ att_s2,
                                            const float* __restrict__ att_d2,
                                            float* __restrict__ ws1,
                                            float* __restrict__ wd1,
                                            float* __restrict__ ws2,
                                            float* __restrict__ wd2) {
  int b = blockIdx.x, tid = threadIdx.x;
  if (b < EB) {
    int e = b * 256 + tid;
    if (e < E_TOT) {
      int dst = (e < N_EDGES) ? ei[N_EDGES + e] : (e - N_EDGES);
      epos[e] = atomicAdd(&deg[dst], 1);
    }
    return;
  }
  if (b < EB + 128) {
    // W1[512x256] -> B1'[j=0..127][k=h*256+c]: B1'[j][h*256+c] = W1[h*128+j][c]
    int k4 = (b - EB) * 256 + tid;                 // 32768 float4
    float4 v = ((const float4*)W1)[k4];
    __half2 h01 = __float22half2_rn(make_float2(v.x, v.y));
    __half2 h23 = __float22half2_rn(make_float2(v.z, v.w));
    uint2 pk = make_uint2(*(u32*)&h01, *(u32*)&h23);
    int r = k4 >> 6, h = r >> 7, j = r & 127;      // r = W1 row, 4 elems/chunk
    ((uint2*)B1)[j * 256 + h * 64 + (k4 & 63)] = pk;
    return;
  }
  if (b < EB + 192) {
    // W2[512x128] -> B2'[j][h*128+c] = W2[h*128+j][c]
    int k4 = (b - EB - 128) * 256 + tid;           // 16384 float4
    float4 v = ((const float4*)W2)[k4];
    __half2 h01 = __float22half2_rn(make_float2(v.x, v.y));
    __half2 h23 = __float22half2_rn(make_float2(v.z, v.w));
    uint2 pk = make_uint2(*(u32*)&h01, *(u32*)&h23);
    int r = k4 >> 5, h = r >> 7, j = r & 127;
    ((uint2*)B2)[j * 128 + h * 32 + (k4 & 31)] = pk;
    return;
  }
  // w~ vectors: w~[h][k] = sum_c att[h][c] * W[h*128+c][k]
  int bw = b - (EB + 192);                         // 0..15
  int h = bw & 3;
  if (bw < 8) {
    const float* att = (bw < 4) ? att_s1 : att_d1;
    float* o = (bw < 4) ? ws1 : wd1;
    int k = tid;                                   // 0..255
    float acc = 0.f;
    for (int c = 0; c < 128; ++c)
      acc = fmaf(att[h * 128 + c], W1[(size_t)(h * 128 + c) * 256 + k], acc);
    o[h * 256 + k] = acc;
  } else {
    const float* att = (bw < 12) ? att_s2 : att_d2;
    float* o = (bw < 12) ? ws2 : wd2;
    if (tid < 128) {
      int k = tid;
      float acc = 0.f;
      for (int c = 0; c < 128; ++c)
        acc = fmaf(att[h * 128 + c], W2[(size_t)(h * 128 + c) * 128 + k], acc);
      o[h * 128 + k] = acc;
    }
  }
}

// ---------------- device-wide degree scan (3 tiny launches) ----------------

__global__ __launch_bounds__(256) void scan_blocks(const int* __restrict__ deg,
                                                   int* __restrict__ row_ptr,
                                                   int* __restrict__ bsum) {
  __shared__ int sh[256];
  int tid = threadIdx.x;
  int idx = blockIdx.x * 256 + tid;
  int v = (idx < N_NODES) ? deg[idx] : 0;
  sh[tid] = v;
  __syncthreads();
#pragma unroll
  for (int off = 1; off < 256; off <<= 1) {
    int t = (tid >= off) ? sh[tid - off] : 0;
    __syncthreads();
    sh[tid] += t;
    __syncthreads();
  }
  if (idx < N_NODES) row_ptr[idx + 1] = sh[tid];
  if (tid == 255) bsum[blockIdx.x] = sh[255];
}

__global__ __launch_bounds__(256) void scan_tops(int* __restrict__ bsum) {
  __shared__ int sh[256];
  int tid = threadIdx.x;
  int v = (tid < SBLK) ? bsum[tid] : 0;
  sh[tid] = v;
  __syncthreads();
#pragma unroll
  for (int off = 1; off < 256; off <<= 1) {
    int t = (tid >= off) ? sh[tid - off] : 0;
    __syncthreads();
    sh[tid] += t;
    __syncthreads();
  }
  if (tid < SBLK) bsum[tid] = sh[tid] - v;   // exclusive
}

__global__ __launch_bounds__(256) void scan_add(const int* __restrict__ bsum,
                                                int* __restrict__ row_ptr) {
  int idx = blockIdx.x * 256 + threadIdx.x;
  int off = bsum[blockIdx.x];
  if (idx < N_NODES) row_ptr[idx + 1] += off;
  if (idx == 0) row_ptr[0] = 0;
}

__device__ __forceinline__ float leaky_exp(float a) {
  a = (a >= 0.f) ? a : NEG_SLOPE * a;
  return __expf(a);
}

// ---------------- scatter: no atomics, one packed 8B write per edge --------

__global__ __launch_bounds__(256) void scatter_pos(const int* __restrict__ ei,
                                                   const int* __restrict__ epos,
                                                   const int* __restrict__ row_ptr,
                                                   int2* __restrict__ col2) {
  int e = blockIdx.x * 256 + threadIdx.x;
  if (e >= E_TOT) return;
  int src, dst;
  if (e < N_EDGES) { src = ei[e]; dst = ei[N_EDGES + e]; }
  else             { src = e - N_EDGES; dst = src; }
  int slot = row_ptr[dst] + epos[e];
  col2[slot] = make_int2(src, dst);
}

// ---------------- edge weights in CSR-slot order (both layers) -------------
// col2[i] sequential; as_[src] random 16B (L2-resident, 800KB);
// ad_[dst] nearly sequential (CSR-sorted); wtab write coalesced.

__global__ __launch_bounds__(256) void edge_weights(const int2* __restrict__ col2,
                                                    const float* __restrict__ as_,
                                                    const float* __restrict__ ad_,
                                                    float4* __restrict__ wtab) {
  int i = blockIdx.x * 256 + threadIdx.x;
  if (i >= E_TOT) return;
  int2 sd = col2[i];
  float4 a = ((const float4*)as_)[sd.x];
  float4 d = ((const float4*)ad_)[sd.y];
  float4 w;
  w.x = leaky_exp(a.x + d.x);
  w.y = leaky_exp(a.y + d.y);
  w.z = leaky_exp(a.z + d.z);
  w.w = leaky_exp(a.w + d.w);
  wtab[i] = w;
}

// ---------------- prep_x: x fp32->fp16 cast + layer-1 scores ----------------
// one wave per node: lane holds 4 channels; 8 dots via full-wave butterfly.

__global__ __launch_bounds__(256) void prep_x(const float* __restrict__ x,
                                              const float* __restrict__ ws1,
                                              const float* __restrict__ wd1,
                                              __half* __restrict__ x16,
                                              float* __restrict__ as_,
                                              float* __restrict__ ad_) {
  int node = (blockIdx.x * 256 + threadIdx.x) >> 6;
  if (node >= N_NODES) return;
  int lane = threadIdx.x & 63;
  int c4 = lane * 4;
  f32x4 xv = *(const f32x4*)(x + (size_t)node * 256 + c4);
  __half2 h01 = __float22half2_rn(make_float2(xv[0], xv[1]));
  __half2 h23 = __float22half2_rn(make_float2(xv[2], xv[3]));
  uint2 pk = make_uint2(*(u32*)&h01, *(u32*)&h23);
  *(uint2*)(x16 + (size_t)node * 256 + c4) = pk;
  float p[8];
#pragma unroll
  for (int v = 0; v < 4; ++v) {
    f32x4 w = *(const f32x4*)(ws1 + v * 256 + c4);
    p[v] = xv[0] * w[0] + xv[1] * w[1] + xv[2] * w[2] + xv[3] * w[3];
    f32x4 u = *(const f32x4*)(wd1 + v * 256 + c4);
    p[4 + v] = xv[0] * u[0] + xv[1] * u[1] + xv[2] * u[2] + xv[3] * u[3];
  }
#pragma unroll
  for (int k = 0; k < 8; ++k)
#pragma unroll
    for (int m = 1; m < 64; m <<= 1)
      p[k] += __shfl_xor(p[k], m, 64);
  if (lane == 0) {
    *(float4*)(as_ + (size_t)node * 4) = make_float4(p[0], p[1], p[2], p[3]);
    *(float4*)(ad_ + (size_t)node * 4) = make_float4(p[4], p[5], p[6], p[7]);
  }
}

// ---------------- score2: layer-2 scores from h (128 ch fp16) ---------------

__global__ __launch_bounds__(256) void score2(const __half* __restrict__ hrow,
                                              const float* __restrict__ ws2,
                                              const float* __restrict__ wd2,
                                              float* __restrict__ as_,
                                              float* __restrict__ ad_) {
  int node = (blockIdx.x * 256 + threadIdx.x) >> 6;
  if (node >= N_NODES) return;
  int lane = threadIdx.x & 63, c = lane * 2;
  float2 f = __half22float2(*(const __half2*)(hrow + (size_t)node * 128 + c));
  float p[8];
#pragma unroll
  for (int v = 0; v < 4; ++v) {
    float2 w = *(const float2*)(ws2 + v * 128 + c);
    p[v] = f.x * w.x + f.y * w.y;
    float2 u = *(const float2*)(wd2 + v * 128 + c);
    p[4 + v] = f.x * u.x + f.y * u.y;
  }
#pragma unroll
  for (int k = 0; k < 8; ++k)
#pragma unroll
    for (int m = 1; m < 64; m <<= 1)
      p[k] += __shfl_xor(p[k], m, 64);
  if (lane == 0) {
    *(float4*)(as_ + (size_t)node * 4) = make_float4(p[0], p[1], p[2], p[3]);
    *(float4*)(ad_ + (size_t)node * 4) = make_float4(p[4], p[5], p[6], p[7]);
  }
}

// ---------------- pre-transform aggregation with PRECOMPUTED weights -------
// one wave per dst node; lane holds CPL channels; weights w[e,h] read as a
// sequential 16B broadcast (CSR-slot order). readfirstlane on bounds/src ->
// SGPR base + lane-offset gather (saddr), scalarizable col/w loads.

template <int CPL>   // 4 -> CHIN=256 (layer 1), 2 -> CHIN=128 (layer 2)
__global__ __launch_bounds__(256) void gat_aggregate_w(
    const __half* __restrict__ tbl, const float4* __restrict__ wtab,
    const int* __restrict__ row_ptr, const int2* __restrict__ col2,
    __half* __restrict__ agg) {
  constexpr int CHIN = CPL * 64;
  const int* colx = (const int*)col2;               // .x at index 2*i
  int node = (blockIdx.x * 256 + threadIdx.x) >> 6;   // wave-uniform
  if (node >= N_NODES) return;
  int lane = threadIdx.x & 63, cb = lane * CPL;
  const __half* tb = tbl + cb;
  int s = __builtin_amdgcn_readfirstlane(row_ptr[node]);
  int e = __builtin_amdgcn_readfirstlane(row_ptr[node + 1]);

  float acc[4][CPL];
#pragma unroll
  for (int h = 0; h < 4; ++h)
#pragma unroll
    for (int c = 0; c < CPL; ++c) acc[h][c] = 0.f;
  float den[4] = {0.f, 0.f, 0.f, 0.f};

  auto accum = [&](uint2 q, float4 w) {
    float wv[4] = {w.x, w.y, w.z, w.w};
#pragma unroll
    for (int h = 0; h < 4; ++h) den[h] += wv[h];
    float f[CPL];
    float2 f0 = __half22float2(*(__half2*)&q.x);
    f[0] = f0.x; f[1] = f0.y;
    if (CPL == 4) {
      float2 f1 = __half22float2(*(__half2*)&q.y);
      f[2] = f1.x; f[3] = f1.y;
    }
#pragma unroll
    for (int h = 0; h < 4; ++h)
#pragma unroll
      for (int c = 0; c < CPL; ++c)
        acc[h][c] = fmaf(wv[h], f[c], acc[h][c]);
  };
  auto loadq = [&](int src) -> uint2 {
    if (CPL == 4) return *(const uint2*)(tb + (size_t)src * CHIN);
    uint2 r; r.x = *(const u32*)(tb + (size_t)src * CHIN); r.y = 0;
    return r;
  };

  int i = s;
  for (; i + 4 <= e; i += 4) {
    int s0 = __builtin_amdgcn_readfirstlane(colx[2 * i]);
    int s1 = __builtin_amdgcn_readfirstlane(colx[2 * i + 2]);
    int s2 = __builtin_amdgcn_readfirstlane(colx[2 * i + 4]);
    int s3 = __builtin_amdgcn_readfirstlane(colx[2 * i + 6]);
    float4 w0 = wtab[i],     w1 = wtab[i + 1];
    float4 w2 = wtab[i + 2], w3 = wtab[i + 3];
    uint2 q0 = loadq(s0), q1 = loadq(s1), q2 = loadq(s2), q3 = loadq(s3);
    accum(q0, w0); accum(q1, w1); accum(q2, w2); accum(q3, w3);
  }
  for (; i < e; ++i) {
    int s0 = __builtin_amdgcn_readfirstlane(colx[2 * i]);
    float4 w0 = wtab[i];
    accum(loadq(s0), w0);
  }

#pragma unroll
  for (int h = 0; h < 4; ++h) {
    float inv = 1.f / (den[h] + 1e-16f);
    if (CPL == 4) {
      __half2 o0 = __float22half2_rn(make_float2(acc[h][0] * inv, acc[h][1] * inv));
      __half2 o1 = __float22half2_rn(make_float2(acc[h][2] * inv, acc[h][3] * inv));
      *(uint2*)(agg + (size_t)node * 4 * CHIN + h * CHIN + cb) =
          make_uint2(*(u32*)&o0, *(u32*)&o1);
    } else {
      __half2 o0 = __float22half2_rn(make_float2(acc[h][0] * inv, acc[h][1] * inv));
      *(u32*)(agg + (size_t)node * 4 * CHIN + h * CHIN + cb) = *(u32*)&o0;
    }
  }
}

// ---------------- post-aggregation GEMM: out = 0.25 * A @ B'^T + bias ------
// A[MPAD x K] fp16 (agg, head-concat K), B'[128 x K] fp16, out [MPAD x 128].
// 256x128 tile, 512 thr = 8 waves (4 row x 2 col), 16 MFMA/step/wave.

#define GLD16(gp, lp)                                                          \
  __builtin_amdgcn_global_load_lds(                                            \
      (const __attribute__((address_space(1))) u32*)(gp),                      \
      (__attribute__((address_space(3))) u32*)(lp), 16, 0, 0)

template <int K, bool HALF_OUT>
__global__ __launch_bounds__(512, 4) void gemm_mean(
    const __half* __restrict__ A, const __half* __restrict__ Bm,
    const float* __restrict__ bias, void* __restrict__ outv) {
  __shared__ u16 sA[256 * 32];   // 16 KB
  __shared__ u16 sB[128 * 32];   // 8 KB
  const int tid = threadIdx.x, lane = tid & 63, wave = tid >> 6;
  const int m0 = blockIdx.x * 256;
  const int wm = (wave >> 1) * 64, wn = (wave & 1) * 64;
  const int t = lane & 15, quad = lane >> 4;

  f32x4 acc[4][4];
#pragma unroll
  for (int i = 0; i < 4; i++)
#pragma unroll
    for (int j = 0; j < 4; j++) acc[i][j] = (f32x4){0.f, 0.f, 0.f, 0.f};

  const char* gpA[2]; u32 offA[2];
#pragma unroll
  for (int r = 0; r < 2; ++r) {
    int c = tid + r * 512;              // 1024 chunks: 256 rows x 4
    int row = c >> 2, w16 = c & 3;
    gpA[r] = (const char*)A + ((size_t)(m0 + row) * K) * 2 + w16 * 16;
    offA[r] = (u32)c * 16;
  }
  const char* gpB;
  {
    int row = tid >> 2, w16 = tid & 3;  // 512 chunks: 128 rows x 4
    gpB = (const char*)Bm + ((size_t)row * K) * 2 + w16 * 16;
  }
  u32 offB = (u32)tid * 16;

  for (int k0 = 0; k0 < K; k0 += 32) {
    __syncthreads();
#pragma unroll
    for (int r = 0; r < 2; ++r) { GLD16(gpA[r], (char*)sA + offA[r]); gpA[r] += 64; }
    GLD16(gpB, (char*)sB + offB); gpB += 64;
    __syncthreads();

    f16x8 a[4], b[4];
#pragma unroll
    for (int i = 0; i < 4; ++i) {
      a[i] = *(const f16x8*)&sA[(wm + t + i * 16) * 32 + quad * 8];
      b[i] = *(const f16x8*)&sB[(wn + t + i * 16) * 32 + quad * 8];
    }
#pragma unroll
    for (int i = 0; i < 4; ++i)
#pragma unroll
      for (int j = 0; j < 4; ++j)
        acc[i][j] = __builtin_amdgcn_mfma_f32_16x16x32_f16(a[i], b[j], acc[i][j], 0, 0, 0);
  }

  float bv[4];
#pragma unroll
  for (int j = 0; j < 4; ++j) bv[j] = bias[wn + j * 16 + t];
#pragma unroll
  for (int i = 0; i < 4; ++i)
#pragma unroll
    for (int j = 0; j < 4; ++j)
#pragma unroll
      for (int r = 0; r < 4; ++r) {
        int m = m0 + wm + i * 16 + quad * 4 + r;   // C/D: col=lane&15, row=quad*4+reg
        if (m < N_NODES) {
          int n = wn + j * 16 + t;
          float v = 0.25f * acc[i][j][r] + bv[j];
          if (HALF_OUT) ((__half*)outv)[(size_t)m * 128 + n] = __float2half(v);
          else          ((float*)outv)[(size_t)m * 128 + n] = v;
        }
      }
}

// ---------------- launch ----------------

extern "C" void kernel_launch(void* const* d_in, const int* in_sizes, int n_in,
                              void* d_out, int out_size, void* d_ws, size_t ws_size,
                              hipStream_t stream) {
  const float* x      = (const float*)d_in[0];
  const int*   ei     = (const int*)  d_in[1];
  const float* W1     = (const float*)d_in[2];
  const float* att_s1 = (const float*)d_in[3];
  const float* att_d1 = (const float*)d_in[4];
  const float* b1     = (const float*)d_in[5];
  const float* W2     = (const float*)d_in[6];
  const float* att_s2 = (const float*)d_in[7];
  const float* att_d2 = (const float*)d_in[8];
  const float* b2     = (const float*)d_in[9];
  float* out = (float*)d_out;

  char* ws = (char*)d_ws;
  size_t off = 0;
  auto alloc = [&](size_t bytes) -> void* {
    void* p = ws + off;
    off += (bytes + 255) & ~(size_t)255;
    return p;
  };
  __half* x16  = (__half*)alloc((size_t)MPAD * 256 * 2);    // 25.7 MB
  __half* agg1 = (__half*)alloc((size_t)MPAD * 1024 * 2);   // 102.8 MB
  __half* B1p  = (__half*)alloc((size_t)128 * 1024 * 2);
  __half* B2p  = (__half*)alloc((size_t)128 * 512 * 2);
  float* ws1 = (float*)alloc(4 * 256 * 4);
  float* wd1 = (float*)alloc(4 * 256 * 4);
  float* ws2 = (float*)alloc(4 * 128 * 4);
  float* wd2 = (float*)alloc(4 * 128 * 4);
  float* as1 = (float*)alloc((size_t)N_NODES * 4 * 4);
  float* ad1 = (float*)alloc((size_t)N_NODES * 4 * 4);
  float* as2 = (float*)alloc((size_t)N_NODES * 4 * 4);
  float* ad2 = (float*)alloc((size_t)N_NODES * 4 * 4);
  int*   row_ptr = (int*)alloc((size_t)(N_NODES + 1) * 4);
  int*   deg     = (int*)alloc((size_t)N_NODES * 4);
  int*   bsum    = (int*)alloc((size_t)256 * 4);
  int*   epos    = (int*)alloc((size_t)E_TOT * 4);          // 3.4 MB
  int2*  col2    = (int2*)alloc((size_t)E_TOT * 8);         // 6.8 MB
  float4* wtab   = (float4*)alloc((size_t)E_TOT * 16);      // 13.6 MB

  // lifetime aliases (stream-ordered, no concurrent use):
  //   out1 (12.8 MB)  reuses x16   (x16 dead after aggregate-1)
  //   agg2 (51.4 MB)  reuses agg1  (agg1 dead after gemm_mean-1)
  __half* out1 = x16;
  __half* agg2 = agg1;

  const int edge_blocks = (E_TOT + 255) / 256;
  const int node_wave_blocks = (N_NODES + 3) / 4;   // 12500

  hipMemsetAsync(deg, 0, (size_t)N_NODES * 4, stream);
  prep<<<EB + 208, 256, 0, stream>>>(ei, deg, epos, W1, B1p, W2, B2p,
                                     att_s1, att_d1, att_s2, att_d2,
                                     ws1, wd1, ws2, wd2);
  scan_blocks<<<SBLK, 256, 0, stream>>>(deg, row_ptr, bsum);
  scan_tops<<<1, 256, 0, stream>>>(bsum);
  scan_add<<<SBLK, 256, 0, stream>>>(bsum, row_ptr);
  scatter_pos<<<edge_blocks, 256, 0, stream>>>(ei, epos, row_ptr, col2);

  // layer 1
  prep_x<<<node_wave_blocks, 256, 0, stream>>>(x, ws1, wd1, x16, as1, ad1);
  edge_weights<<<edge_blocks, 256, 0, stream>>>(col2, as1, ad1, wtab);
  gat_aggregate_w<4><<<node_wave_blocks, 256, 0, stream>>>(
      x16, wtab, row_ptr, col2, agg1);
  gemm_mean<1024, true><<<MPAD / 256, 512, 0, stream>>>(agg1, B1p, b1, out1);

  // layer 2
  score2<<<node_wave_blocks, 256, 0, stream>>>(out1, ws2, wd2, as2, ad2);
  edge_weights<<<edge_blocks, 256, 0, stream>>>(col2, as2, ad2, wtab);
  gat_aggregate_w<2><<<node_wave_blocks, 256, 0, stream>>>(
      out1, wtab, row_ptr, col2, agg2);
  gemm_mean<512, false><<<MPAD / 256, 512, 0, stream>>>(agg2, B2p, b2, out);
}

// Round 8
// 395.602 us; speedup vs baseline: 1.5048x; 1.0278x over previous
//
#include <hip/hip_runtime.h>
#include <hip/hip_fp16.h>
#include <math.h>

#define N_NODES 50000
#define MPAD    50176              /* padded rows = 784*64 */
#define N_EDGES 800000
#define E_TOT   (N_EDGES + N_NODES)
#define EB      ((E_TOT + 255) / 256)   /* 3321 edge blocks in prep */
#define HEADS   4
#define NEG_SLOPE 0.2f
#define SBLK    ((N_NODES + 255) / 256)  /* 196 scan blocks */

typedef unsigned int u32;
typedef unsigned short u16;
typedef __attribute__((ext_vector_type(8))) _Float16 f16x8;
typedef __attribute__((ext_vector_type(4))) float f32x4;

// =====================================================================
// DUAL-FORM GAT (r14): aggregate PRE-transform features, GEMM after.
// r14 changes vs r13:
//   - gemm_mean: BM 256 -> 64 (grid 196 -> 784 = ~3 blocks/CU; the old
//     196-block grid left 60 CUs idle and gave the 2-barrier K-loop no
//     cross-block overlap to hide the per-step staging drain)
//   - gat_aggregate_w: 8-edge unroll (was 4) -> 2x outstanding gathers;
//     kernel was 55% HBM / 40% VALU at 24 VGPR = ILP-starved, not
//     byte-starved
// =====================================================================

// ---------------- prep: degree count (+epos) + W permute-casts + w~ ---------

__global__ __launch_bounds__(256) void prep(const int* __restrict__ ei,
                                            int* __restrict__ deg,
                                            int* __restrict__ epos,
                                            const float* __restrict__ W1,
                                            __half* __restrict__ B1,
                                            const float* __restrict__ W2,
                                            __half* __restrict__ B2,
                                            const float* __restrict__ att_s1,
                                            const float* __restrict__ att_d1,
                                            const float* __restrict__ att_s2,
                                            const float* __restrict__ att_d2,
                                            float* __restrict__ ws1,
                                            float* __restrict__ wd1,
                                            float* __restrict__ ws2,
                                            float* __restrict__ wd2) {
  int b = blockIdx.x, tid = threadIdx.x;
  if (b < EB) {
    int e = b * 256 + tid;
    if (e < E_TOT) {
      int dst = (e < N_EDGES) ? ei[N_EDGES + e] : (e - N_EDGES);
      epos[e] = atomicAdd(&deg[dst], 1);
    }
    return;
  }
  if (b < EB + 128) {
    // W1[512x256] -> B1'[j=0..127][k=h*256+c]: B1'[j][h*256+c] = W1[h*128+j][c]
    int k4 = (b - EB) * 256 + tid;                 // 32768 float4
    float4 v = ((const float4*)W1)[k4];
    __half2 h01 = __float22half2_rn(make_float2(v.x, v.y));
    __half2 h23 = __float22half2_rn(make_float2(v.z, v.w));
    uint2 pk = make_uint2(*(u32*)&h01, *(u32*)&h23);
    int r = k4 >> 6, h = r >> 7, j = r & 127;      // r = W1 row, 4 elems/chunk
    ((uint2*)B1)[j * 256 + h * 64 + (k4 & 63)] = pk;
    return;
  }
  if (b < EB + 192) {
    // W2[512x128] -> B2'[j][h*128+c] = W2[h*128+j][c]
    int k4 = (b - EB - 128) * 256 + tid;           // 16384 float4
    float4 v = ((const float4*)W2)[k4];
    __half2 h01 = __float22half2_rn(make_float2(v.x, v.y));
    __half2 h23 = __float22half2_rn(make_float2(v.z, v.w));
    uint2 pk = make_uint2(*(u32*)&h01, *(u32*)&h23);
    int r = k4 >> 5, h = r >> 7, j = r & 127;
    ((uint2*)B2)[j * 128 + h * 32 + (k4 & 31)] = pk;
    return;
  }
  // w~ vectors: w~[h][k] = sum_c att[h][c] * W[h*128+c][k]
  int bw = b - (EB + 192);                         // 0..15
  int h = bw & 3;
  if (bw < 8) {
    const float* att = (bw < 4) ? att_s1 : att_d1;
    float* o = (bw < 4) ? ws1 : wd1;
    int k = tid;                                   // 0..255
    float acc = 0.f;
    for (int c = 0; c < 128; ++c)
      acc = fmaf(att[h * 128 + c], W1[(size_t)(h * 128 + c) * 256 + k], acc);
    o[h * 256 + k] = acc;
  } else {
    const float* att = (bw < 12) ? att_s2 : att_d2;
    float* o = (bw < 12) ? ws2 : wd2;
    if (tid < 128) {
      int k = tid;
      float acc = 0.f;
      for (int c = 0; c < 128; ++c)
        acc = fmaf(att[h * 128 + c], W2[(size_t)(h * 128 + c) * 128 + k], acc);
      o[h * 128 + k] = acc;
    }
  }
}

// ---------------- device-wide degree scan (3 tiny launches) ----------------

__global__ __launch_bounds__(256) void scan_blocks(const int* __restrict__ deg,
                                                   int* __restrict__ row_ptr,
                                                   int* __restrict__ bsum) {
  __shared__ int sh[256];
  int tid = threadIdx.x;
  int idx = blockIdx.x * 256 + tid;
  int v = (idx < N_NODES) ? deg[idx] : 0;
  sh[tid] = v;
  __syncthreads();
#pragma unroll
  for (int off = 1; off < 256; off <<= 1) {
    int t = (tid >= off) ? sh[tid - off] : 0;
    __syncthreads();
    sh[tid] += t;
    __syncthreads();
  }
  if (idx < N_NODES) row_ptr[idx + 1] = sh[tid];
  if (tid == 255) bsum[blockIdx.x] = sh[255];
}

__global__ __launch_bounds__(256) void scan_tops(int* __restrict__ bsum) {
  __shared__ int sh[256];
  int tid = threadIdx.x;
  int v = (tid < SBLK) ? bsum[tid] : 0;
  sh[tid] = v;
  __syncthreads();
#pragma unroll
  for (int off = 1; off < 256; off <<= 1) {
    int t = (tid >= off) ? sh[tid - off] : 0;
    __syncthreads();
    sh[tid] += t;
    __syncthreads();
  }
  if (tid < SBLK) bsum[tid] = sh[tid] - v;   // exclusive
}

__global__ __launch_bounds__(256) void scan_add(const int* __restrict__ bsum,
                                                int* __restrict__ row_ptr) {
  int idx = blockIdx.x * 256 + threadIdx.x;
  int off = bsum[blockIdx.x];
  if (idx < N_NODES) row_ptr[idx + 1] += off;
  if (idx == 0) row_ptr[0] = 0;
}

__device__ __forceinline__ float leaky_exp(float a) {
  a = (a >= 0.f) ? a : NEG_SLOPE * a;
  return __expf(a);
}

// ---------------- scatter: no atomics, one packed 8B write per edge --------

__global__ __launch_bounds__(256) void scatter_pos(const int* __restrict__ ei,
                                                   const int* __restrict__ epos,
                                                   const int* __restrict__ row_ptr,
                                                   int2* __restrict__ col2) {
  int e = blockIdx.x * 256 + threadIdx.x;
  if (e >= E_TOT) return;
  int src, dst;
  if (e < N_EDGES) { src = ei[e]; dst = ei[N_EDGES + e]; }
  else             { src = e - N_EDGES; dst = src; }
  int slot = row_ptr[dst] + epos[e];
  col2[slot] = make_int2(src, dst);
}

// ---------------- edge weights in CSR-slot order (both layers) -------------

__global__ __launch_bounds__(256) void edge_weights(const int2* __restrict__ col2,
                                                    const float* __restrict__ as_,
                                                    const float* __restrict__ ad_,
                                                    float4* __restrict__ wtab) {
  int i = blockIdx.x * 256 + threadIdx.x;
  if (i >= E_TOT) return;
  int2 sd = col2[i];
  float4 a = ((const float4*)as_)[sd.x];
  float4 d = ((const float4*)ad_)[sd.y];
  float4 w;
  w.x = leaky_exp(a.x + d.x);
  w.y = leaky_exp(a.y + d.y);
  w.z = leaky_exp(a.z + d.z);
  w.w = leaky_exp(a.w + d.w);
  wtab[i] = w;
}

// ---------------- prep_x: x fp32->fp16 cast + layer-1 scores ----------------

__global__ __launch_bounds__(256) void prep_x(const float* __restrict__ x,
                                              const float* __restrict__ ws1,
                                              const float* __restrict__ wd1,
                                              __half* __restrict__ x16,
                                              float* __restrict__ as_,
                                              float* __restrict__ ad_) {
  int node = (blockIdx.x * 256 + threadIdx.x) >> 6;
  if (node >= N_NODES) return;
  int lane = threadIdx.x & 63;
  int c4 = lane * 4;
  f32x4 xv = *(const f32x4*)(x + (size_t)node * 256 + c4);
  __half2 h01 = __float22half2_rn(make_float2(xv[0], xv[1]));
  __half2 h23 = __float22half2_rn(make_float2(xv[2], xv[3]));
  uint2 pk = make_uint2(*(u32*)&h01, *(u32*)&h23);
  *(uint2*)(x16 + (size_t)node * 256 + c4) = pk;
  float p[8];
#pragma unroll
  for (int v = 0; v < 4; ++v) {
    f32x4 w = *(const f32x4*)(ws1 + v * 256 + c4);
    p[v] = xv[0] * w[0] + xv[1] * w[1] + xv[2] * w[2] + xv[3] * w[3];
    f32x4 u = *(const f32x4*)(wd1 + v * 256 + c4);
    p[4 + v] = xv[0] * u[0] + xv[1] * u[1] + xv[2] * u[2] + xv[3] * u[3];
  }
#pragma unroll
  for (int k = 0; k < 8; ++k)
#pragma unroll
    for (int m = 1; m < 64; m <<= 1)
      p[k] += __shfl_xor(p[k], m, 64);
  if (lane == 0) {
    *(float4*)(as_ + (size_t)node * 4) = make_float4(p[0], p[1], p[2], p[3]);
    *(float4*)(ad_ + (size_t)node * 4) = make_float4(p[4], p[5], p[6], p[7]);
  }
}

// ---------------- score2: layer-2 scores from h (128 ch fp16) ---------------

__global__ __launch_bounds__(256) void score2(const __half* __restrict__ hrow,
                                              const float* __restrict__ ws2,
                                              const float* __restrict__ wd2,
                                              float* __restrict__ as_,
                                              float* __restrict__ ad_) {
  int node = (blockIdx.x * 256 + threadIdx.x) >> 6;
  if (node >= N_NODES) return;
  int lane = threadIdx.x & 63, c = lane * 2;
  float2 f = __half22float2(*(const __half2*)(hrow + (size_t)node * 128 + c));
  float p[8];
#pragma unroll
  for (int v = 0; v < 4; ++v) {
    float2 w = *(const float2*)(ws2 + v * 128 + c);
    p[v] = f.x * w.x + f.y * w.y;
    float2 u = *(const float2*)(wd2 + v * 128 + c);
    p[4 + v] = f.x * u.x + f.y * u.y;
  }
#pragma unroll
  for (int k = 0; k < 8; ++k)
#pragma unroll
    for (int m = 1; m < 64; m <<= 1)
      p[k] += __shfl_xor(p[k], m, 64);
  if (lane == 0) {
    *(float4*)(as_ + (size_t)node * 4) = make_float4(p[0], p[1], p[2], p[3]);
    *(float4*)(ad_ + (size_t)node * 4) = make_float4(p[4], p[5], p[6], p[7]);
  }
}

// ---------------- pre-transform aggregation with PRECOMPUTED weights -------
// one wave per dst node; lane holds CPL channels; weights w[e,h] read as a
// sequential 16B broadcast (CSR-slot order). 8-edge unroll (r14): doubles
// outstanding gathers — kernel was ILP-starved at 24 VGPR (55% HBM/40% VALU).

template <int CPL>   // 4 -> CHIN=256 (layer 1), 2 -> CHIN=128 (layer 2)
__global__ __launch_bounds__(256) void gat_aggregate_w(
    const __half* __restrict__ tbl, const float4* __restrict__ wtab,
    const int* __restrict__ row_ptr, const int2* __restrict__ col2,
    __half* __restrict__ agg) {
  constexpr int CHIN = CPL * 64;
  const int* colx = (const int*)col2;               // .x at index 2*i
  int node = (blockIdx.x * 256 + threadIdx.x) >> 6;   // wave-uniform
  if (node >= N_NODES) return;
  int lane = threadIdx.x & 63, cb = lane * CPL;
  const __half* tb = tbl + cb;
  int s = __builtin_amdgcn_readfirstlane(row_ptr[node]);
  int e = __builtin_amdgcn_readfirstlane(row_ptr[node + 1]);

  float acc[4][CPL];
#pragma unroll
  for (int h = 0; h < 4; ++h)
#pragma unroll
    for (int c = 0; c < CPL; ++c) acc[h][c] = 0.f;
  float den[4] = {0.f, 0.f, 0.f, 0.f};

  auto accum = [&](uint2 q, float4 w) {
    float wv[4] = {w.x, w.y, w.z, w.w};
#pragma unroll
    for (int h = 0; h < 4; ++h) den[h] += wv[h];
    float f[CPL];
    float2 f0 = __half22float2(*(__half2*)&q.x);
    f[0] = f0.x; f[1] = f0.y;
    if (CPL == 4) {
      float2 f1 = __half22float2(*(__half2*)&q.y);
      f[2] = f1.x; f[3] = f1.y;
    }
#pragma unroll
    for (int h = 0; h < 4; ++h)
#pragma unroll
      for (int c = 0; c < CPL; ++c)
        acc[h][c] = fmaf(wv[h], f[c], acc[h][c]);
  };
  auto loadq = [&](int src) -> uint2 {
    if (CPL == 4) return *(const uint2*)(tb + (size_t)src * CHIN);
    uint2 r; r.x = *(const u32*)(tb + (size_t)src * CHIN); r.y = 0;
    return r;
  };

  int i = s;
  for (; i + 8 <= e; i += 8) {
    int sn[8];
#pragma unroll
    for (int k = 0; k < 8; ++k)
      sn[k] = __builtin_amdgcn_readfirstlane(colx[2 * (i + k)]);
    float4 wv[8];
#pragma unroll
    for (int k = 0; k < 8; ++k) wv[k] = wtab[i + k];
    uint2 q[8];
#pragma unroll
    for (int k = 0; k < 8; ++k) q[k] = loadq(sn[k]);
#pragma unroll
    for (int k = 0; k < 8; ++k) accum(q[k], wv[k]);
  }
  for (; i + 4 <= e; i += 4) {
    int s0 = __builtin_amdgcn_readfirstlane(colx[2 * i]);
    int s1 = __builtin_amdgcn_readfirstlane(colx[2 * i + 2]);
    int s2 = __builtin_amdgcn_readfirstlane(colx[2 * i + 4]);
    int s3 = __builtin_amdgcn_readfirstlane(colx[2 * i + 6]);
    float4 w0 = wtab[i],     w1 = wtab[i + 1];
    float4 w2 = wtab[i + 2], w3 = wtab[i + 3];
    uint2 q0 = loadq(s0), q1 = loadq(s1), q2 = loadq(s2), q3 = loadq(s3);
    accum(q0, w0); accum(q1, w1); accum(q2, w2); accum(q3, w3);
  }
  for (; i < e; ++i) {
    int s0 = __builtin_amdgcn_readfirstlane(colx[2 * i]);
    float4 w0 = wtab[i];
    accum(loadq(s0), w0);
  }

#pragma unroll
  for (int h = 0; h < 4; ++h) {
    float inv = 1.f / (den[h] + 1e-16f);
    if (CPL == 4) {
      __half2 o0 = __float22half2_rn(make_float2(acc[h][0] * inv, acc[h][1] * inv));
      __half2 o1 = __float22half2_rn(make_float2(acc[h][2] * inv, acc[h][3] * inv));
      *(uint2*)(agg + (size_t)node * 4 * CHIN + h * CHIN + cb) =
          make_uint2(*(u32*)&o0, *(u32*)&o1);
    } else {
      __half2 o0 = __float22half2_rn(make_float2(acc[h][0] * inv, acc[h][1] * inv));
      *(u32*)(agg + (size_t)node * 4 * CHIN + h * CHIN + cb) = *(u32*)&o0;
    }
  }
}

// ---------------- post-aggregation GEMM: out = 0.25 * A @ B'^T + bias ------
// A[MPAD x K] fp16 (agg, head-concat K), B'[128 x K] fp16, out [MPAD x 128].
// r14: 64x128 tile, 256 thr = 4 waves (2 row x 2 col), acc[2][4], 12 KB LDS.
// Grid 784 = ~3 blocks/CU (was 196 = <1/CU: 60 CUs idle, no cross-block
// overlap to hide the per-K-step staging drain).

#define GLD16(gp, lp)                                                          \
  __builtin_amdgcn_global_load_lds(                                            \
      (const __attribute__((address_space(1))) u32*)(gp),                      \
      (__attribute__((address_space(3))) u32*)(lp), 16, 0, 0)

template <int K, bool HALF_OUT>
__global__ __launch_bounds__(256, 4) void gemm_mean(
    const __half* __restrict__ A, const __half* __restrict__ Bm,
    const float* __restrict__ bias, void* __restrict__ outv) {
  __shared__ u16 sA[64 * 32];    // 4 KB
  __shared__ u16 sB[128 * 32];   // 8 KB
  const int tid = threadIdx.x, lane = tid & 63, wave = tid >> 6;  // 0..3
  const int m0 = blockIdx.x * 64;
  const int wm = (wave >> 1) * 32, wn = (wave & 1) * 64;
  const int t = lane & 15, quad = lane >> 4;

  f32x4 acc[2][4];
#pragma unroll
  for (int i = 0; i < 2; i++)
#pragma unroll
    for (int j = 0; j < 4; j++) acc[i][j] = (f32x4){0.f, 0.f, 0.f, 0.f};

  const char* gpA; u32 offA;
  {
    int row = tid >> 2, w16 = tid & 3;  // 256 chunks: 64 rows x 4
    gpA = (const char*)A + ((size_t)(m0 + row) * K) * 2 + w16 * 16;
    offA = (u32)tid * 16;
  }
  const char* gpB[2]; u32 offB[2];
#pragma unroll
  for (int r = 0; r < 2; ++r) {
    int c = tid + r * 256;              // 512 chunks: 128 rows x 4
    int row = c >> 2, w16 = c & 3;
    gpB[r] = (const char*)Bm + ((size_t)row * K) * 2 + w16 * 16;
    offB[r] = (u32)c * 16;
  }

  for (int k0 = 0; k0 < K; k0 += 32) {
    __syncthreads();
    GLD16(gpA, (char*)sA + offA); gpA += 64;
#pragma unroll
    for (int r = 0; r < 2; ++r) { GLD16(gpB[r], (char*)sB + offB[r]); gpB[r] += 64; }
    __syncthreads();

    f16x8 a[2], b[4];
#pragma unroll
    for (int i = 0; i < 2; ++i)
      a[i] = *(const f16x8*)&sA[(wm + t + i * 16) * 32 + quad * 8];
#pragma unroll
    for (int j = 0; j < 4; ++j)
      b[j] = *(const f16x8*)&sB[(wn + t + j * 16) * 32 + quad * 8];
#pragma unroll
    for (int i = 0; i < 2; ++i)
#pragma unroll
      for (int j = 0; j < 4; ++j)
        acc[i][j] = __builtin_amdgcn_mfma_f32_16x16x32_f16(a[i], b[j], acc[i][j], 0, 0, 0);
  }

  float bv[4];
#pragma unroll
  for (int j = 0; j < 4; ++j) bv[j] = bias[wn + j * 16 + t];
#pragma unroll
  for (int i = 0; i < 2; ++i)
#pragma unroll
    for (int j = 0; j < 4; ++j)
#pragma unroll
      for (int r = 0; r < 4; ++r) {
        int m = m0 + wm + i * 16 + quad * 4 + r;   // C/D: col=lane&15, row=quad*4+reg
        if (m < N_NODES) {
          int n = wn + j * 16 + t;
          float v = 0.25f * acc[i][j][r] + bv[j];
          if (HALF_OUT) ((__half*)outv)[(size_t)m * 128 + n] = __float2half(v);
          else          ((float*)outv)[(size_t)m * 128 + n] = v;
        }
      }
}

// ---------------- launch ----------------

extern "C" void kernel_launch(void* const* d_in, const int* in_sizes, int n_in,
                              void* d_out, int out_size, void* d_ws, size_t ws_size,
                              hipStream_t stream) {
  const float* x      = (const float*)d_in[0];
  const int*   ei     = (const int*)  d_in[1];
  const float* W1     = (const float*)d_in[2];
  const float* att_s1 = (const float*)d_in[3];
  const float* att_d1 = (const float*)d_in[4];
  const float* b1     = (const float*)d_in[5];
  const float* W2     = (const float*)d_in[6];
  const float* att_s2 = (const float*)d_in[7];
  const float* att_d2 = (const float*)d_in[8];
  const float* b2     = (const float*)d_in[9];
  float* out = (float*)d_out;

  char* ws = (char*)d_ws;
  size_t off = 0;
  auto alloc = [&](size_t bytes) -> void* {
    void* p = ws + off;
    off += (bytes + 255) & ~(size_t)255;
    return p;
  };
  __half* x16  = (__half*)alloc((size_t)MPAD * 256 * 2);    // 25.7 MB
  __half* agg1 = (__half*)alloc((size_t)MPAD * 1024 * 2);   // 102.8 MB
  __half* B1p  = (__half*)alloc((size_t)128 * 1024 * 2);
  __half* B2p  = (__half*)alloc((size_t)128 * 512 * 2);
  float* ws1 = (float*)alloc(4 * 256 * 4);
  float* wd1 = (float*)alloc(4 * 256 * 4);
  float* ws2 = (float*)alloc(4 * 128 * 4);
  float* wd2 = (float*)alloc(4 * 128 * 4);
  float* as1 = (float*)alloc((size_t)N_NODES * 4 * 4);
  float* ad1 = (float*)alloc((size_t)N_NODES * 4 * 4);
  float* as2 = (float*)alloc((size_t)N_NODES * 4 * 4);
  float* ad2 = (float*)alloc((size_t)N_NODES * 4 * 4);
  int*   row_ptr = (int*)alloc((size_t)(N_NODES + 1) * 4);
  int*   deg     = (int*)alloc((size_t)N_NODES * 4);
  int*   bsum    = (int*)alloc((size_t)256 * 4);
  int*   epos    = (int*)alloc((size_t)E_TOT * 4);          // 3.4 MB
  int2*  col2    = (int2*)alloc((size_t)E_TOT * 8);         // 6.8 MB
  float4* wtab   = (float4*)alloc((size_t)E_TOT * 16);      // 13.6 MB

  // lifetime aliases (stream-ordered, no concurrent use):
  //   out1 (12.8 MB)  reuses x16   (x16 dead after aggregate-1)
  //   agg2 (51.4 MB)  reuses agg1  (agg1 dead after gemm_mean-1)
  __half* out1 = x16;
  __half* agg2 = agg1;

  const int edge_blocks = (E_TOT + 255) / 256;
  const int node_wave_blocks = (N_NODES + 3) / 4;   // 12500

  hipMemsetAsync(deg, 0, (size_t)N_NODES * 4, stream);
  prep<<<EB + 208, 256, 0, stream>>>(ei, deg, epos, W1, B1p, W2, B2p,
                                     att_s1, att_d1, att_s2, att_d2,
                                     ws1, wd1, ws2, wd2);
  scan_blocks<<<SBLK, 256, 0, stream>>>(deg, row_ptr, bsum);
  scan_tops<<<1, 256, 0, stream>>>(bsum);
  scan_add<<<SBLK, 256, 0, stream>>>(bsum, row_ptr);
  scatter_pos<<<edge_blocks, 256, 0, stream>>>(ei, epos, row_ptr, col2);

  // layer 1
  prep_x<<<node_wave_blocks, 256, 0, stream>>>(x, ws1, wd1, x16, as1, ad1);
  edge_weights<<<edge_blocks, 256, 0, stream>>>(col2, as1, ad1, wtab);
  gat_aggregate_w<4><<<node_wave_blocks, 256, 0, stream>>>(
      x16, wtab, row_ptr, col2, agg1);
  gemm_mean<1024, true><<<MPAD / 64, 256, 0, stream>>>(agg1, B1p, b1, out1);

  // layer 2
  score2<<<node_wave_blocks, 256, 0, stream>>>(out1, ws2, wd2, as2, ad2);
  edge_weights<<<edge_blocks, 256, 0, stream>>>(col2, as2, ad2, wtab);
  gat_aggregate_w<2><<<node_wave_blocks, 256, 0, stream>>>(
      out1, wtab, row_ptr, col2, agg2);
  gemm_mean<512, false><<<MPAD / 64, 256, 0, stream>>>(agg2, B2p, b2, out);
}